// Round 1
// baseline (2617.084 us; speedup 1.0000x reference)
//
#include <hip/hip_runtime.h>
#include <hip/hip_bf16.h>
#include <math.h>

// ---------------- degree / dinv ----------------

__global__ void count_deg_kernel(const int* __restrict__ dst, float* __restrict__ deg, int E) {
    int e = blockIdx.x * blockDim.x + threadIdx.x;
    if (e < E) atomicAdd(&deg[dst[e]], 1.0f);
}

__global__ void finalize_dinv_kernel(float* __restrict__ deg, int n) {
    int i = blockIdx.x * blockDim.x + threadIdx.x;
    if (i < n) deg[i] = rsqrtf(deg[i] + 1.0f);
}

// ---------------- fp32 tiled GEMM: C[M,N] = (relu?)A[M,K] @ W[K,N] ----------------
// 64x64 tile, 256 threads, 4x4 per thread, BK=16.

#define BM 64
#define BN 64
#define BK 16

__global__ __launch_bounds__(256) void gemm_kernel(
    const float* __restrict__ A, const float* __restrict__ W, float* __restrict__ C,
    int M, int N, int K, int relu_a)
{
    __shared__ float As[BK][BM + 1];
    __shared__ float Bs[BK][BN + 1];

    const int tid = threadIdx.x;
    const int tx = tid & 15;        // 0..15  (cols)
    const int ty = tid >> 4;        // 0..15  (rows)
    const int row0 = blockIdx.x * BM;
    const int col0 = blockIdx.y * BN;

    float acc[4][4];
#pragma unroll
    for (int i = 0; i < 4; i++)
#pragma unroll
        for (int j = 0; j < 4; j++) acc[i][j] = 0.f;

    for (int k0 = 0; k0 < K; k0 += BK) {
        // Load A tile: BM x BK, coalesced along K (i%BK fastest)
#pragma unroll
        for (int i = tid; i < BM * BK; i += 256) {
            int r = i >> 4;          // / BK
            int kk = i & 15;         // % BK
            int gr = row0 + r, gk = k0 + kk;
            float v = (gr < M && gk < K) ? A[(size_t)gr * K + gk] : 0.f;
            if (relu_a) v = fmaxf(v, 0.f);
            As[kk][r] = v;
        }
        // Load W tile: BK x BN, coalesced along N (i%BN fastest)
#pragma unroll
        for (int i = tid; i < BK * BN; i += 256) {
            int c = i & 63;          // % BN
            int kk = i >> 6;         // / BN
            int gc = col0 + c, gk = k0 + kk;
            Bs[kk][c] = (gk < K && gc < N) ? W[(size_t)gk * N + gc] : 0.f;
        }
        __syncthreads();

#pragma unroll
        for (int kk = 0; kk < BK; kk++) {
            float a[4], b[4];
#pragma unroll
            for (int i = 0; i < 4; i++) a[i] = As[kk][ty * 4 + i];
#pragma unroll
            for (int j = 0; j < 4; j++) b[j] = Bs[kk][tx * 4 + j];
#pragma unroll
            for (int i = 0; i < 4; i++)
#pragma unroll
                for (int j = 0; j < 4; j++) acc[i][j] += a[i] * b[j];
        }
        __syncthreads();
    }

#pragma unroll
    for (int i = 0; i < 4; i++) {
        int gr = row0 + ty * 4 + i;
        if (gr >= M) continue;
#pragma unroll
        for (int j = 0; j < 4; j++) {
            int gc = col0 + tx * 4 + j;
            if (gc < N) C[(size_t)gr * N + gc] = acc[i][j];
        }
    }
}

// ---------------- self-loop + bias init: out[i,f] = h[i,f]*dinv[i]^2 + b[f] ----------------

__global__ void selfloop_bias_kernel(const float* __restrict__ h, float* __restrict__ out,
                                     const float* __restrict__ dinv, const float* __restrict__ bias,
                                     int n, int F)
{
    long long idx = (long long)blockIdx.x * blockDim.x + threadIdx.x;
    long long total = (long long)n * F;
    if (idx >= total) return;
    int i = (int)(idx / F);
    int c = (int)(idx % F);
    float di = dinv[i];
    out[idx] = h[idx] * di * di + bias[c];
}

// ---------------- edge scatter (F multiple of 4): out[dst] += h[src]*dinv[src]*dinv[dst] ----------------

__global__ void scatter_edges_f4_kernel(const float* __restrict__ h, float* __restrict__ out,
                                        const int* __restrict__ src, const int* __restrict__ dst,
                                        const float* __restrict__ dinv, int E, int F4)
{
    long long idx = (long long)blockIdx.x * blockDim.x + threadIdx.x;
    long long total = (long long)E * F4;
    if (idx >= total) return;
    int e = (int)(idx / F4);
    int c = (int)(idx % F4);
    int s = src[e], d = dst[e];
    float w = dinv[s] * dinv[d];
    const float4* hp = (const float4*)(h + (size_t)s * (F4 * 4));
    float4 v = hp[c];
    float* op = out + (size_t)d * (F4 * 4) + (size_t)c * 4;
    atomicAdd(op + 0, v.x * w);
    atomicAdd(op + 1, v.y * w);
    atomicAdd(op + 2, v.z * w);
    atomicAdd(op + 3, v.w * w);
}

// scalar variant for F=10
__global__ void scatter_edges_s_kernel(const float* __restrict__ h, float* __restrict__ out,
                                       const int* __restrict__ src, const int* __restrict__ dst,
                                       const float* __restrict__ dinv, int E, int F)
{
    long long idx = (long long)blockIdx.x * blockDim.x + threadIdx.x;
    long long total = (long long)E * F;
    if (idx >= total) return;
    int e = (int)(idx / F);
    int c = (int)(idx % F);
    int s = src[e], d = dst[e];
    float w = dinv[s] * dinv[d];
    atomicAdd(out + (size_t)d * F + c, h[(size_t)s * F + c] * w);
}

// ---------------- small GEMM: C[M,10] = relu(A[M,512]) @ W[512,10], wave-per-row ----------------

__global__ __launch_bounds__(256) void gemm_small_kernel(
    const float* __restrict__ A, const float* __restrict__ W, float* __restrict__ C,
    int M, int K, int relu_a)
{
    __shared__ float Ws[512 * 10];
    for (int i = threadIdx.x; i < K * 10; i += blockDim.x) Ws[i] = W[i];
    __syncthreads();

    const int wave = threadIdx.x >> 6;
    const int lane = threadIdx.x & 63;
    const int row = blockIdx.x * (blockDim.x >> 6) + wave;
    if (row >= M) return;

    float acc[10];
#pragma unroll
    for (int c = 0; c < 10; c++) acc[c] = 0.f;

    for (int k = lane; k < K; k += 64) {
        float a = A[(size_t)row * K + k];
        if (relu_a) a = fmaxf(a, 0.f);
#pragma unroll
        for (int c = 0; c < 10; c++) acc[c] += a * Ws[k * 10 + c];
    }
#pragma unroll
    for (int c = 0; c < 10; c++) {
#pragma unroll
        for (int off = 32; off; off >>= 1) acc[c] += __shfl_down(acc[c], off);
    }
    if (lane == 0) {
#pragma unroll
        for (int c = 0; c < 10; c++) C[(size_t)row * 10 + c] = acc[c];
    }
}

// ---------------- log_softmax over 10 classes, thread-per-row ----------------

__global__ void logsoftmax10_kernel(const float* __restrict__ logits, float* __restrict__ out, int n)
{
    int i = blockIdx.x * blockDim.x + threadIdx.x;
    if (i >= n) return;
    float v[10];
    float m = -1e30f;
#pragma unroll
    for (int c = 0; c < 10; c++) { v[c] = logits[(size_t)i * 10 + c]; m = fmaxf(m, v[c]); }
    float s = 0.f;
#pragma unroll
    for (int c = 0; c < 10; c++) s += __expf(v[c] - m);
    float ls = m + __logf(s);
#pragma unroll
    for (int c = 0; c < 10; c++) out[(size_t)i * 10 + c] = v[c] - ls;
}

// ---------------- launch ----------------

extern "C" void kernel_launch(void* const* d_in, const int* in_sizes, int n_in,
                              void* d_out, int out_size, void* d_ws, size_t ws_size,
                              hipStream_t stream)
{
    const float* x   = (const float*)d_in[0];
    const int*   ei  = (const int*)d_in[1];
    const float* W1  = (const float*)d_in[2];
    const float* b1  = (const float*)d_in[3];
    const float* W2  = (const float*)d_in[4];
    const float* b2  = (const float*)d_in[5];
    const float* Wc  = (const float*)d_in[6];
    const float* bc  = (const float*)d_in[7];
    float* out = (float*)d_out;

    const int IN_FEATS = 784;
    const int H = 512;
    const int NC = 10;
    const int n = in_sizes[0] / IN_FEATS;   // 10000
    const int E = in_sizes[1] / 2;          // 160000
    const int* src = ei;
    const int* dst = ei + E;

    // workspace layout
    char* ws = (char*)d_ws;
    float* bufA   = (float*)ws;                 ws += (size_t)n * H * sizeof(float);   // h (pre-agg)
    float* bufB   = (float*)ws;                 ws += (size_t)n * H * sizeof(float);   // agg (pre-relu)
    float* dinv   = (float*)ws;                 ws += (size_t)n * sizeof(float);
    float* h3     = (float*)ws;                 ws += (size_t)n * NC * sizeof(float);
    float* logits = (float*)ws;                 ws += (size_t)n * NC * sizeof(float);

    // ---- degrees ----
    hipMemsetAsync(dinv, 0, (size_t)n * sizeof(float), stream);
    count_deg_kernel<<<(E + 255) / 256, 256, 0, stream>>>(dst, dinv, E);
    finalize_dinv_kernel<<<(n + 255) / 256, 256, 0, stream>>>(dinv, n);

    dim3 gemm_block(256);
    dim3 gemm_grid1((n + BM - 1) / BM, H / BN);

    // ---- layer 1: h1 = x @ W1 ----
    gemm_kernel<<<gemm_grid1, gemm_block, 0, stream>>>(x, W1, bufA, n, H, IN_FEATS, 0);
    {
        long long total = (long long)n * H;
        selfloop_bias_kernel<<<(int)((total + 255) / 256), 256, 0, stream>>>(bufA, bufB, dinv, b1, n, H);
        long long stotal = (long long)E * (H / 4);
        scatter_edges_f4_kernel<<<(int)((stotal + 255) / 256), 256, 0, stream>>>(bufA, bufB, src, dst, dinv, E, H / 4);
    }

    // ---- layer 2: h2 = relu(agg1) @ W2 ----
    gemm_kernel<<<gemm_grid1, gemm_block, 0, stream>>>(bufB, W2, bufA, n, H, H, 1);
    {
        long long total = (long long)n * H;
        selfloop_bias_kernel<<<(int)((total + 255) / 256), 256, 0, stream>>>(bufA, bufB, dinv, b2, n, H);
        long long stotal = (long long)E * (H / 4);
        scatter_edges_f4_kernel<<<(int)((stotal + 255) / 256), 256, 0, stream>>>(bufA, bufB, src, dst, dinv, E, H / 4);
    }

    // ---- layer 3: h3 = relu(agg2) @ Wc ----
    gemm_small_kernel<<<(n + 3) / 4, 256, 0, stream>>>(bufB, Wc, h3, n, H, 1);
    {
        long long total = (long long)n * NC;
        selfloop_bias_kernel<<<(int)((total + 255) / 256), 256, 0, stream>>>(h3, logits, dinv, bc, n, NC);
        long long stotal = (long long)E * NC;
        scatter_edges_s_kernel<<<(int)((stotal + 255) / 256), 256, 0, stream>>>(h3, logits, src, dst, dinv, E, NC);
    }

    // ---- log_softmax ----
    logsoftmax10_kernel<<<(n + 255) / 256, 256, 0, stream>>>(logits, out, n);
}

// Round 2
// 633.815 us; speedup vs baseline: 4.1291x; 4.1291x over previous
//
#include <hip/hip_runtime.h>
#include <hip/hip_bf16.h>
#include <math.h>

// ---------------- degree count (int) ----------------

__global__ void count_deg_kernel(const int* __restrict__ dst, int* __restrict__ deg, int E) {
    int e = blockIdx.x * blockDim.x + threadIdx.x;
    if (e < E) atomicAdd(&deg[dst[e]], 1);
}

// ---------------- one-block exclusive scan over deg -> row_start; also dinv ----------------
// n = 10000, 40 iterations of a 256-wide Hillis-Steele scan. Single block.

__global__ __launch_bounds__(256) void scan_kernel(const int* __restrict__ deg,
                                                   int* __restrict__ row_start,
                                                   float* __restrict__ dinv, int n)
{
    __shared__ int sdata[256];
    __shared__ int s_running;
    if (threadIdx.x == 0) s_running = 0;
    __syncthreads();

    for (int base = 0; base < n; base += 256) {
        int i = base + threadIdx.x;
        int v = (i < n) ? deg[i] : 0;
        sdata[threadIdx.x] = v;
        __syncthreads();
        for (int off = 1; off < 256; off <<= 1) {
            int t = (threadIdx.x >= off) ? sdata[threadIdx.x - off] : 0;
            __syncthreads();
            sdata[threadIdx.x] += t;
            __syncthreads();
        }
        int incl = sdata[threadIdx.x];
        if (i < n) {
            row_start[i] = s_running + incl - v;
            dinv[i] = rsqrtf((float)v + 1.0f);
        }
        __syncthreads();
        if (threadIdx.x == 0) s_running += sdata[255];
        __syncthreads();
    }
    if (threadIdx.x == 0) row_start[n] = s_running;
}

// ---------------- CSR fill: csr_src[row_start[d] + cursor[d]++] = src[e] ----------------

__global__ void fill_csr_kernel(const int* __restrict__ src, const int* __restrict__ dst,
                                const int* __restrict__ row_start, int* __restrict__ cursor,
                                int* __restrict__ csr_src, int E)
{
    int e = blockIdx.x * blockDim.x + threadIdx.x;
    if (e >= E) return;
    int d = dst[e];
    int pos = row_start[d] + atomicAdd(&cursor[d], 1);
    csr_src[pos] = src[e];
}

// ---------------- fp32 tiled GEMM: C[M,N] = (relu?)A[M,K] @ W[K,N] ----------------

#define BM 64
#define BN 64
#define BK 16

__global__ __launch_bounds__(256) void gemm_kernel(
    const float* __restrict__ A, const float* __restrict__ W, float* __restrict__ C,
    int M, int N, int K, int relu_a)
{
    __shared__ float As[BK][BM + 1];
    __shared__ float Bs[BK][BN + 1];

    const int tid = threadIdx.x;
    const int tx = tid & 15;
    const int ty = tid >> 4;
    const int row0 = blockIdx.x * BM;
    const int col0 = blockIdx.y * BN;

    float acc[4][4];
#pragma unroll
    for (int i = 0; i < 4; i++)
#pragma unroll
        for (int j = 0; j < 4; j++) acc[i][j] = 0.f;

    for (int k0 = 0; k0 < K; k0 += BK) {
#pragma unroll
        for (int i = tid; i < BM * BK; i += 256) {
            int r = i >> 4;
            int kk = i & 15;
            int gr = row0 + r, gk = k0 + kk;
            float v = (gr < M && gk < K) ? A[(size_t)gr * K + gk] : 0.f;
            if (relu_a) v = fmaxf(v, 0.f);
            As[kk][r] = v;
        }
#pragma unroll
        for (int i = tid; i < BK * BN; i += 256) {
            int c = i & 63;
            int kk = i >> 6;
            int gc = col0 + c, gk = k0 + kk;
            Bs[kk][c] = (gk < K && gc < N) ? W[(size_t)gk * N + gc] : 0.f;
        }
        __syncthreads();

#pragma unroll
        for (int kk = 0; kk < BK; kk++) {
            float a[4], b[4];
#pragma unroll
            for (int i = 0; i < 4; i++) a[i] = As[kk][ty * 4 + i];
#pragma unroll
            for (int j = 0; j < 4; j++) b[j] = Bs[kk][tx * 4 + j];
#pragma unroll
            for (int i = 0; i < 4; i++)
#pragma unroll
                for (int j = 0; j < 4; j++) acc[i][j] += a[i] * b[j];
        }
        __syncthreads();
    }

#pragma unroll
    for (int i = 0; i < 4; i++) {
        int gr = row0 + ty * 4 + i;
        if (gr >= M) continue;
#pragma unroll
        for (int j = 0; j < 4; j++) {
            int gc = col0 + tx * 4 + j;
            if (gc < N) C[(size_t)gr * N + gc] = acc[i][j];
        }
    }
}

// ---------------- gather aggregation, F=512: block per dst node, 2 feats/thread ----------------
// out[i] = sum_{e: dst=i} h[src_e]*dinv[src_e]*dinv[i]  +  h[i]*dinv[i]^2  +  bias

__global__ __launch_bounds__(256) void gather512_kernel(
    const float* __restrict__ h, float* __restrict__ out,
    const int* __restrict__ csr_src, const int* __restrict__ row_start,
    const float* __restrict__ dinv, const float* __restrict__ bias, int n)
{
    const int node = blockIdx.x;
    const int f = threadIdx.x;            // features f and f+256
    const float di = dinv[node];

    const size_t base = (size_t)node * 512;
    float acc0 = h[base + f] * di * di + bias[f];
    float acc1 = h[base + f + 256] * di * di + bias[f + 256];

    const int beg = row_start[node], end = row_start[node + 1];
    for (int p = beg; p < end; ++p) {
        int s = csr_src[p];
        float w = dinv[s] * di;
        const size_t sb = (size_t)s * 512;
        acc0 += h[sb + f] * w;
        acc1 += h[sb + f + 256] * w;
    }
    out[base + f] = acc0;
    out[base + f + 256] = acc1;
}

// ---------------- gather aggregation, F=10: thread per (node, class) ----------------

__global__ void gather10_kernel(
    const float* __restrict__ h, float* __restrict__ out,
    const int* __restrict__ csr_src, const int* __restrict__ row_start,
    const float* __restrict__ dinv, const float* __restrict__ bias, int n)
{
    int idx = blockIdx.x * blockDim.x + threadIdx.x;
    if (idx >= n * 10) return;
    int node = idx / 10;
    int c = idx % 10;
    float di = dinv[node];
    float acc = h[(size_t)node * 10 + c] * di * di + bias[c];
    int beg = row_start[node], end = row_start[node + 1];
    for (int p = beg; p < end; ++p) {
        int s = csr_src[p];
        acc += h[(size_t)s * 10 + c] * dinv[s] * di;
    }
    out[idx] = acc;
}

// ---------------- small GEMM: C[M,10] = relu(A[M,512]) @ W[512,10], wave-per-row ----------------

__global__ __launch_bounds__(256) void gemm_small_kernel(
    const float* __restrict__ A, const float* __restrict__ W, float* __restrict__ C,
    int M, int K, int relu_a)
{
    __shared__ float Ws[512 * 10];
    for (int i = threadIdx.x; i < K * 10; i += blockDim.x) Ws[i] = W[i];
    __syncthreads();

    const int wave = threadIdx.x >> 6;
    const int lane = threadIdx.x & 63;
    const int row = blockIdx.x * (blockDim.x >> 6) + wave;
    if (row >= M) return;

    float acc[10];
#pragma unroll
    for (int c = 0; c < 10; c++) acc[c] = 0.f;

    for (int k = lane; k < K; k += 64) {
        float a = A[(size_t)row * K + k];
        if (relu_a) a = fmaxf(a, 0.f);
#pragma unroll
        for (int c = 0; c < 10; c++) acc[c] += a * Ws[k * 10 + c];
    }
#pragma unroll
    for (int c = 0; c < 10; c++) {
#pragma unroll
        for (int off = 32; off; off >>= 1) acc[c] += __shfl_down(acc[c], off);
    }
    if (lane == 0) {
#pragma unroll
        for (int c = 0; c < 10; c++) C[(size_t)row * 10 + c] = acc[c];
    }
}

// ---------------- log_softmax over 10 classes ----------------

__global__ void logsoftmax10_kernel(const float* __restrict__ logits, float* __restrict__ out, int n)
{
    int i = blockIdx.x * blockDim.x + threadIdx.x;
    if (i >= n) return;
    float v[10];
    float m = -1e30f;
#pragma unroll
    for (int c = 0; c < 10; c++) { v[c] = logits[(size_t)i * 10 + c]; m = fmaxf(m, v[c]); }
    float s = 0.f;
#pragma unroll
    for (int c = 0; c < 10; c++) s += __expf(v[c] - m);
    float ls = m + __logf(s);
#pragma unroll
    for (int c = 0; c < 10; c++) out[(size_t)i * 10 + c] = v[c] - ls;
}

// ---------------- launch ----------------

extern "C" void kernel_launch(void* const* d_in, const int* in_sizes, int n_in,
                              void* d_out, int out_size, void* d_ws, size_t ws_size,
                              hipStream_t stream)
{
    const float* x   = (const float*)d_in[0];
    const int*   ei  = (const int*)d_in[1];
    const float* W1  = (const float*)d_in[2];
    const float* b1  = (const float*)d_in[3];
    const float* W2  = (const float*)d_in[4];
    const float* b2  = (const float*)d_in[5];
    const float* Wc  = (const float*)d_in[6];
    const float* bc  = (const float*)d_in[7];
    float* out = (float*)d_out;

    const int IN_FEATS = 784;
    const int H = 512;
    const int NC = 10;
    const int n = in_sizes[0] / IN_FEATS;   // 10000
    const int E = in_sizes[1] / 2;          // 160000
    const int* src = ei;
    const int* dst = ei + E;

    // workspace layout (~41.8 MB)
    char* ws = (char*)d_ws;
    float* bufA      = (float*)ws;  ws += (size_t)n * H * sizeof(float);   // 20.48 MB
    float* bufB      = (float*)ws;  ws += (size_t)n * H * sizeof(float);   // 20.48 MB
    float* dinv      = (float*)ws;  ws += (size_t)n * sizeof(float);
    int*   deg       = (int*)ws;    ws += (size_t)n * sizeof(int);
    int*   row_start = (int*)ws;    ws += (size_t)(n + 1) * sizeof(int);
    int*   cursor    = (int*)ws;    ws += (size_t)n * sizeof(int);
    int*   csr_src   = (int*)ws;    ws += (size_t)E * sizeof(int);
    // layer-3 small buffers reuse bufA's region (free after gather2)
    float* h3     = bufA;
    float* logits = bufA + (size_t)n * NC;

    // ---- CSR build + dinv ----
    hipMemsetAsync(deg, 0, (size_t)n * sizeof(int), stream);
    hipMemsetAsync(cursor, 0, (size_t)n * sizeof(int), stream);
    count_deg_kernel<<<(E + 255) / 256, 256, 0, stream>>>(dst, deg, E);
    scan_kernel<<<1, 256, 0, stream>>>(deg, row_start, dinv, n);
    fill_csr_kernel<<<(E + 255) / 256, 256, 0, stream>>>(src, dst, row_start, cursor, csr_src, E);

    dim3 gemm_block(256);
    dim3 gemm_grid1((n + BM - 1) / BM, H / BN);

    // ---- layer 1: h1 = x @ W1 ; agg1 = gather(h1) ----
    gemm_kernel<<<gemm_grid1, gemm_block, 0, stream>>>(x, W1, bufA, n, H, IN_FEATS, 0);
    gather512_kernel<<<n, 256, 0, stream>>>(bufA, bufB, csr_src, row_start, dinv, b1, n);

    // ---- layer 2: h2 = relu(agg1) @ W2 ; agg2 = gather(h2) ----
    gemm_kernel<<<gemm_grid1, gemm_block, 0, stream>>>(bufB, W2, bufA, n, H, H, 1);
    gather512_kernel<<<n, 256, 0, stream>>>(bufA, bufB, csr_src, row_start, dinv, b2, n);

    // ---- layer 3: h3 = relu(agg2) @ Wc ; logits = gather(h3) ----
    gemm_small_kernel<<<(n + 3) / 4, 256, 0, stream>>>(bufB, Wc, h3, n, H, 1);
    gather10_kernel<<<(n * NC + 255) / 256, 256, 0, stream>>>(h3, logits, csr_src, row_start, dinv, bc, n);

    // ---- log_softmax ----
    logsoftmax10_kernel<<<(n + 255) / 256, 256, 0, stream>>>(logits, out, n);
}

// Round 3
// 605.393 us; speedup vs baseline: 4.3230x; 1.0469x over previous
//
#include <hip/hip_runtime.h>
#include <hip/hip_bf16.h>
#include <math.h>

typedef __attribute__((ext_vector_type(8))) short short8;
typedef __attribute__((ext_vector_type(4))) float f32x4;

__device__ inline unsigned short f2bf(float f) {
    unsigned int u = __float_as_uint(f);
    unsigned int r = u + 0x7fffu + ((u >> 16) & 1u);   // RTNE
    return (unsigned short)(r >> 16);
}
__device__ inline float bf2f(unsigned short h) {
    return __uint_as_float(((unsigned int)h) << 16);
}

// ---------------- degree count ----------------

__global__ void count_deg_kernel(const int* __restrict__ dst, int* __restrict__ deg, int E) {
    int e = blockIdx.x * blockDim.x + threadIdx.x;
    if (e < E) atomicAdd(&deg[dst[e]], 1);
}

// ---------------- one-block scan -> row_start; also dinv ----------------

__global__ __launch_bounds__(256) void scan_kernel(const int* __restrict__ deg,
                                                   int* __restrict__ row_start,
                                                   float* __restrict__ dinv, int n)
{
    __shared__ int sdata[256];
    __shared__ int s_running;
    if (threadIdx.x == 0) s_running = 0;
    __syncthreads();

    for (int base = 0; base < n; base += 256) {
        int i = base + threadIdx.x;
        int v = (i < n) ? deg[i] : 0;
        sdata[threadIdx.x] = v;
        __syncthreads();
        for (int off = 1; off < 256; off <<= 1) {
            int t = (threadIdx.x >= off) ? sdata[threadIdx.x - off] : 0;
            __syncthreads();
            sdata[threadIdx.x] += t;
            __syncthreads();
        }
        int incl = sdata[threadIdx.x];
        if (i < n) {
            row_start[i] = s_running + incl - v;
            dinv[i] = rsqrtf((float)v + 1.0f);
        }
        __syncthreads();
        if (threadIdx.x == 0) s_running += sdata[255];
        __syncthreads();
    }
    if (threadIdx.x == 0) row_start[n] = s_running;
}

// ---------------- CSR fill ----------------

__global__ void fill_csr_kernel(const int* __restrict__ src, const int* __restrict__ dst,
                                const int* __restrict__ row_start, int* __restrict__ cursor,
                                int* __restrict__ csr_src, int E)
{
    int e = blockIdx.x * blockDim.x + threadIdx.x;
    if (e >= E) return;
    int d = dst[e];
    int pos = row_start[d] + atomicAdd(&cursor[d], 1);
    csr_src[pos] = src[e];
}

// ---------------- W split+transpose: W[K,N] fp32 -> WhT/WlT [N,Kp] bf16 (zero-padded) ----------------

__global__ void convW_kernel(const float* __restrict__ W,
                             unsigned short* __restrict__ WhT, unsigned short* __restrict__ WlT,
                             int K, int N, int Kp)
{
    int id = blockIdx.x * blockDim.x + threadIdx.x;
    if (id >= N * Kp) return;
    int nrow = id / Kp;
    int k = id - nrow * Kp;
    float v = (k < K) ? W[(size_t)k * N + nrow] : 0.f;
    unsigned short h = f2bf(v);
    WhT[id] = h;
    WlT[id] = f2bf(v - bf2f(h));
}

// ---------------- MFMA GEMM: C[M,N] = (relu?)A[M,K] @ W[K,N], fp32-accurate via 3-term bf16 split ----
// Tile 128x64, BK=32, 256 threads (4 waves). A split hi/lo on the fly during staging.
// W pre-split into WhT/WlT [N][Kp] (transposed, bf16, zero-padded to Kp).

#define TBM 128
#define TBN 64
#define TBK 32

__global__ __launch_bounds__(256) void gemm_mfma_kernel(
    const float* __restrict__ A,
    const unsigned short* __restrict__ WhT, const unsigned short* __restrict__ WlT,
    float* __restrict__ C, int M, int N, int K, int Kp, int relu_a)
{
    __shared__ unsigned short Ah[TBM * TBK];   // [m][k] row-major
    __shared__ unsigned short Al[TBM * TBK];
    __shared__ unsigned short Bh[TBN * TBK];   // [n][k] row-major (i.e. B^T)
    __shared__ unsigned short Bl[TBN * TBK];

    const int tid = threadIdx.x;
    const int row0 = blockIdx.x * TBM;
    const int col0 = blockIdx.y * TBN;

    const int wave = tid >> 6;
    const int lane = tid & 63;
    const int quad = lane >> 4;
    const int l16  = lane & 15;
    const int m_base = wave * 32;   // each wave: rows [m_base, m_base+32)

    f32x4 acc[2][4];
#pragma unroll
    for (int b = 0; b < 2; b++)
#pragma unroll
        for (int c = 0; c < 4; c++) acc[b][c] = (f32x4){0.f, 0.f, 0.f, 0.f};

    // A staging indices: thread handles 16 consecutive k's in one row
    const int ar = tid >> 1;              // 0..127
    const int ac0 = (tid & 1) * 16;       // 0 or 16
    // B staging indices: thread loads 8 shorts (16B) of one n-row
    const int bn = tid >> 2;              // 0..63
    const int bc0 = (tid & 3) * 8;        // 0,8,16,24

    for (int k0 = 0; k0 < Kp; k0 += TBK) {
        // ---- stage A (fp32 -> hi/lo bf16) ----
        {
            const int gr = row0 + ar;
#pragma unroll
            for (int i = 0; i < 16; i++) {
                int gk = k0 + ac0 + i;
                float v = (gr < M && gk < K) ? A[(size_t)gr * K + gk] : 0.f;
                if (relu_a) v = fmaxf(v, 0.f);
                unsigned short h = f2bf(v);
                Ah[ar * TBK + ac0 + i] = h;
                Al[ar * TBK + ac0 + i] = f2bf(v - bf2f(h));
            }
        }
        // ---- stage B^T (bf16, vector 16B loads) ----
        {
            const size_t g = (size_t)(col0 + bn) * Kp + k0 + bc0;
            *(uint4*)&Bh[bn * TBK + bc0] = *(const uint4*)&WhT[g];
            *(uint4*)&Bl[bn * TBK + bc0] = *(const uint4*)&WlT[g];
        }
        __syncthreads();

        // ---- fragments + MFMA ----
        short8 ah[2], al[2];
#pragma unroll
        for (int b = 0; b < 2; b++) {
            int off = (m_base + b * 16 + l16) * TBK + quad * 8;
            ah[b] = *(const short8*)&Ah[off];
            al[b] = *(const short8*)&Al[off];
        }
#pragma unroll
        for (int ct = 0; ct < 4; ct++) {
            int off = (ct * 16 + l16) * TBK + quad * 8;
            short8 bh = *(const short8*)&Bh[off];
            short8 bl = *(const short8*)&Bl[off];
#pragma unroll
            for (int b = 0; b < 2; b++) {
                acc[b][ct] = __builtin_amdgcn_mfma_f32_16x16x32_bf16(ah[b], bh, acc[b][ct], 0, 0, 0);
                acc[b][ct] = __builtin_amdgcn_mfma_f32_16x16x32_bf16(ah[b], bl, acc[b][ct], 0, 0, 0);
                acc[b][ct] = __builtin_amdgcn_mfma_f32_16x16x32_bf16(al[b], bh, acc[b][ct], 0, 0, 0);
            }
        }
        __syncthreads();
    }

    // ---- epilogue: C/D layout col=lane&15, row=quad*4+reg ----
#pragma unroll
    for (int b = 0; b < 2; b++) {
#pragma unroll
        for (int ct = 0; ct < 4; ct++) {
            int gc = col0 + ct * 16 + l16;
#pragma unroll
            for (int r = 0; r < 4; r++) {
                int gr = row0 + m_base + b * 16 + quad * 4 + r;
                if (gr < M) C[(size_t)gr * N + gc] = acc[b][ct][r];
            }
        }
    }
}

// ---------------- gather aggregation, F=512 ----------------

__global__ __launch_bounds__(256) void gather512_kernel(
    const float* __restrict__ h, float* __restrict__ out,
    const int* __restrict__ csr_src, const int* __restrict__ row_start,
    const float* __restrict__ dinv, const float* __restrict__ bias, int n)
{
    const int node = blockIdx.x;
    const int f = threadIdx.x;
    const float di = dinv[node];

    const size_t base = (size_t)node * 512;
    float acc0 = h[base + f] * di * di + bias[f];
    float acc1 = h[base + f + 256] * di * di + bias[f + 256];

    const int beg = row_start[node], end = row_start[node + 1];
    for (int p = beg; p < end; ++p) {
        int s = csr_src[p];
        float w = dinv[s] * di;
        const size_t sb = (size_t)s * 512;
        acc0 += h[sb + f] * w;
        acc1 += h[sb + f + 256] * w;
    }
    out[base + f] = acc0;
    out[base + f + 256] = acc1;
}

// ---------------- gather aggregation, F=10 ----------------

__global__ void gather10_kernel(
    const float* __restrict__ h, float* __restrict__ out,
    const int* __restrict__ csr_src, const int* __restrict__ row_start,
    const float* __restrict__ dinv, const float* __restrict__ bias, int n)
{
    int idx = blockIdx.x * blockDim.x + threadIdx.x;
    if (idx >= n * 10) return;
    int node = idx / 10;
    int c = idx % 10;
    float di = dinv[node];
    float acc = h[(size_t)node * 10 + c] * di * di + bias[c];
    int beg = row_start[node], end = row_start[node + 1];
    for (int p = beg; p < end; ++p) {
        int s = csr_src[p];
        acc += h[(size_t)s * 10 + c] * dinv[s] * di;
    }
    out[idx] = acc;
}

// ---------------- small GEMM: C[M,10] = relu(A[M,512]) @ W[512,10] ----------------

__global__ __launch_bounds__(256) void gemm_small_kernel(
    const float* __restrict__ A, const float* __restrict__ W, float* __restrict__ C,
    int M, int K, int relu_a)
{
    __shared__ float Ws[512 * 10];
    for (int i = threadIdx.x; i < K * 10; i += blockDim.x) Ws[i] = W[i];
    __syncthreads();

    const int wave = threadIdx.x >> 6;
    const int lane = threadIdx.x & 63;
    const int row = blockIdx.x * (blockDim.x >> 6) + wave;
    if (row >= M) return;

    float acc[10];
#pragma unroll
    for (int c = 0; c < 10; c++) acc[c] = 0.f;

    for (int k = lane; k < K; k += 64) {
        float a = A[(size_t)row * K + k];
        if (relu_a) a = fmaxf(a, 0.f);
#pragma unroll
        for (int c = 0; c < 10; c++) acc[c] += a * Ws[k * 10 + c];
    }
#pragma unroll
    for (int c = 0; c < 10; c++) {
#pragma unroll
        for (int off = 32; off; off >>= 1) acc[c] += __shfl_down(acc[c], off);
    }
    if (lane == 0) {
#pragma unroll
        for (int c = 0; c < 10; c++) C[(size_t)row * 10 + c] = acc[c];
    }
}

// ---------------- log_softmax over 10 classes ----------------

__global__ void logsoftmax10_kernel(const float* __restrict__ logits, float* __restrict__ out, int n)
{
    int i = blockIdx.x * blockDim.x + threadIdx.x;
    if (i >= n) return;
    float v[10];
    float m = -1e30f;
#pragma unroll
    for (int c = 0; c < 10; c++) { v[c] = logits[(size_t)i * 10 + c]; m = fmaxf(m, v[c]); }
    float s = 0.f;
#pragma unroll
    for (int c = 0; c < 10; c++) s += __expf(v[c] - m);
    float ls = m + __logf(s);
#pragma unroll
    for (int c = 0; c < 10; c++) out[(size_t)i * 10 + c] = v[c] - ls;
}

// ---------------- launch ----------------

extern "C" void kernel_launch(void* const* d_in, const int* in_sizes, int n_in,
                              void* d_out, int out_size, void* d_ws, size_t ws_size,
                              hipStream_t stream)
{
    const float* x   = (const float*)d_in[0];
    const int*   ei  = (const int*)d_in[1];
    const float* W1  = (const float*)d_in[2];
    const float* b1  = (const float*)d_in[3];
    const float* W2  = (const float*)d_in[4];
    const float* b2  = (const float*)d_in[5];
    const float* Wc  = (const float*)d_in[6];
    const float* bc  = (const float*)d_in[7];
    float* out = (float*)d_out;

    const int IN_FEATS = 784;
    const int KP1 = 800;                    // 784 padded to multiple of 32
    const int H = 512;
    const int NC = 10;
    const int n = in_sizes[0] / IN_FEATS;   // 10000
    const int E = in_sizes[1] / 2;          // 160000
    const int* src = ei;
    const int* dst = ei + E;

    // workspace layout (~43.4 MB), 16B-aligned chunks first
    char* ws = (char*)d_ws;
    float* bufA      = (float*)ws;           ws += (size_t)n * H * sizeof(float);        // 20.48 MB
    float* bufB      = (float*)ws;           ws += (size_t)n * H * sizeof(float);        // 20.48 MB
    unsigned short* WhT = (unsigned short*)ws; ws += (size_t)KP1 * H * sizeof(unsigned short); // 0.82 MB
    unsigned short* WlT = (unsigned short*)ws; ws += (size_t)KP1 * H * sizeof(unsigned short); // 0.82 MB
    float* dinv      = (float*)ws;           ws += (size_t)n * sizeof(float);
    int*   deg       = (int*)ws;             ws += (size_t)n * sizeof(int);
    int*   cursor    = (int*)ws;             ws += (size_t)n * sizeof(int);
    int*   csr_src   = (int*)ws;             ws += (size_t)E * sizeof(int);
    int*   row_start = (int*)ws;             ws += (size_t)(n + 1) * sizeof(int);

    float* h3     = bufA;                    // layer-3 small buffers reuse bufA
    float* logits = bufA + (size_t)n * NC;

    // ---- CSR build + dinv ----
    hipMemsetAsync(deg, 0, (size_t)n * sizeof(int), stream);
    hipMemsetAsync(cursor, 0, (size_t)n * sizeof(int), stream);
    count_deg_kernel<<<(E + 255) / 256, 256, 0, stream>>>(dst, deg, E);
    scan_kernel<<<1, 256, 0, stream>>>(deg, row_start, dinv, n);
    fill_csr_kernel<<<(E + 255) / 256, 256, 0, stream>>>(src, dst, row_start, cursor, csr_src, E);

    const int grid_m = (n + TBM - 1) / TBM;   // 79

    // ---- layer 1: h1 = x @ W1 ; agg1 = gather(h1) ----
    convW_kernel<<<(H * KP1 + 255) / 256, 256, 0, stream>>>(W1, WhT, WlT, IN_FEATS, H, KP1);
    gemm_mfma_kernel<<<dim3(grid_m, H / TBN), 256, 0, stream>>>(x, WhT, WlT, bufA, n, H, IN_FEATS, KP1, 0);
    gather512_kernel<<<n, 256, 0, stream>>>(bufA, bufB, csr_src, row_start, dinv, b1, n);

    // ---- layer 2: h2 = relu(agg1) @ W2 ; agg2 = gather(h2) ----
    convW_kernel<<<(H * H + 255) / 256, 256, 0, stream>>>(W2, WhT, WlT, H, H, H);
    gemm_mfma_kernel<<<dim3(grid_m, H / TBN), 256, 0, stream>>>(bufB, WhT, WlT, bufA, n, H, H, H, 1);
    gather512_kernel<<<n, 256, 0, stream>>>(bufA, bufB, csr_src, row_start, dinv, b2, n);

    // ---- layer 3: h3 = relu(agg2) @ Wc ; logits = gather(h3) ----
    gemm_small_kernel<<<(n + 3) / 4, 256, 0, stream>>>(bufB, Wc, h3, n, H, 1);
    gather10_kernel<<<(n * NC + 255) / 256, 256, 0, stream>>>(h3, logits, csr_src, row_start, dinv, bc, n);

    // ---- log_softmax ----
    logsoftmax10_kernel<<<(n + 255) / 256, 256, 0, stream>>>(logits, out, n);
}

// Round 4
// 390.953 us; speedup vs baseline: 6.6941x; 1.5485x over previous
//
#include <hip/hip_runtime.h>
#include <hip/hip_bf16.h>
#include <math.h>

typedef __attribute__((ext_vector_type(8))) short short8;
typedef __attribute__((ext_vector_type(4))) float f32x4;
typedef __attribute__((ext_vector_type(4))) unsigned short us4;

__device__ inline unsigned short f2bf(float f) {
    unsigned int u = __float_as_uint(f);
    unsigned int r = u + 0x7fffu + ((u >> 16) & 1u);   // RTNE
    return (unsigned short)(r >> 16);
}
__device__ inline float bf2f(unsigned short h) {
    return __uint_as_float(((unsigned int)h) << 16);
}

// ---------------- degree count ----------------

__global__ void count_deg_kernel(const int* __restrict__ dst, int* __restrict__ deg, int E) {
    int e = blockIdx.x * blockDim.x + threadIdx.x;
    if (e < E) atomicAdd(&deg[dst[e]], 1);
}

// ---------------- one-block scan -> row_start; also dinv ----------------

__global__ __launch_bounds__(256) void scan_kernel(const int* __restrict__ deg,
                                                   int* __restrict__ row_start,
                                                   float* __restrict__ dinv, int n)
{
    __shared__ int sdata[256];
    __shared__ int s_running;
    if (threadIdx.x == 0) s_running = 0;
    __syncthreads();

    for (int base = 0; base < n; base += 256) {
        int i = base + threadIdx.x;
        int v = (i < n) ? deg[i] : 0;
        sdata[threadIdx.x] = v;
        __syncthreads();
        for (int off = 1; off < 256; off <<= 1) {
            int t = (threadIdx.x >= off) ? sdata[threadIdx.x - off] : 0;
            __syncthreads();
            sdata[threadIdx.x] += t;
            __syncthreads();
        }
        int incl = sdata[threadIdx.x];
        if (i < n) {
            row_start[i] = s_running + incl - v;
            dinv[i] = rsqrtf((float)v + 1.0f);
        }
        __syncthreads();
        if (threadIdx.x == 0) s_running += sdata[255];
        __syncthreads();
    }
    if (threadIdx.x == 0) row_start[n] = s_running;
}

// ---------------- CSR fill ----------------

__global__ void fill_csr_kernel(const int* __restrict__ src, const int* __restrict__ dst,
                                const int* __restrict__ row_start, int* __restrict__ cursor,
                                int* __restrict__ csr_src, int E)
{
    int e = blockIdx.x * blockDim.x + threadIdx.x;
    if (e >= E) return;
    int d = dst[e];
    int pos = row_start[d] + atomicAdd(&cursor[d], 1);
    csr_src[pos] = src[e];
}

// ---------------- W split+transpose: W[K,N] fp32 -> WhT/WlT [N,Kp] bf16 (zero-padded) ----------------

__global__ void convW_kernel(const float* __restrict__ W,
                             unsigned short* __restrict__ WhT, unsigned short* __restrict__ WlT,
                             int K, int N, int Kp)
{
    int id = blockIdx.x * blockDim.x + threadIdx.x;
    if (id >= N * Kp) return;
    int nrow = id / Kp;
    int k = id - nrow * Kp;
    float v = (k < K) ? W[(size_t)k * N + nrow] : 0.f;
    unsigned short h = f2bf(v);
    WhT[id] = h;
    WlT[id] = f2bf(v - bf2f(h));
}

// ---------------- MFMA GEMM: C[M,N] = (relu?)A[M,K] @ W[K,N], 3-term bf16 split ----------------
// Tile 64x128, BK=32, 256 threads (4 waves). A: coalesced float4 loads, on-the-fly hi/lo split.
// LDS rows padded to TBK+8 shorts -> conflict-free ds_read_b128 fragments.

#define TBM 64
#define TBN 128
#define TBK 32
#define LDA (TBK + 8)   // padded row length in shorts

__global__ __launch_bounds__(256) void gemm_mfma_kernel(
    const float* __restrict__ A,
    const unsigned short* __restrict__ WhT, const unsigned short* __restrict__ WlT,
    float* __restrict__ C, int M, int N, int K, int Kp, int tiles_m, int relu_a)
{
    __shared__ unsigned short Ah[TBM * LDA];
    __shared__ unsigned short Al[TBM * LDA];
    __shared__ unsigned short Bh[TBN * LDA];
    __shared__ unsigned short Bl[TBN * LDA];

    const int tid = threadIdx.x;
    const int g = blockIdx.x;
    const int tm = g % tiles_m;          // row tile (fast-moving -> first sweep warms L3 with A)
    const int tn = g / tiles_m;          // col tile
    const int row0 = tm * TBM;
    const int col0 = tn * TBN;

    const int wave = tid >> 6;
    const int lane = tid & 63;
    const int quad = lane >> 4;
    const int l16  = lane & 15;
    const int rh = (wave & 1) * 32;      // wave row-half: 32 rows
    const int ch = (wave >> 1) * 64;     // wave col-half: 64 cols

    f32x4 acc[2][4];
#pragma unroll
    for (int b = 0; b < 2; b++)
#pragma unroll
        for (int c = 0; c < 4; c++) acc[b][c] = (f32x4){0.f, 0.f, 0.f, 0.f};

    for (int k0 = 0; k0 < Kp; k0 += TBK) {
        // ---- stage A: 64 rows x 32 k, float4 per thread, 2 passes ----
#pragma unroll
        for (int p = 0; p < 2; p++) {
            int i = p * 256 + tid;            // 0..511 float4 chunks
            int r = i >> 3;                   // 0..63
            int kc = (i & 7) * 4;             // 0..28
            int gr = row0 + r, gk = k0 + kc;
            float4 v = make_float4(0.f, 0.f, 0.f, 0.f);
            if (gr < M && gk < K) v = *(const float4*)&A[(size_t)gr * K + gk];
            if (relu_a) {
                v.x = fmaxf(v.x, 0.f); v.y = fmaxf(v.y, 0.f);
                v.z = fmaxf(v.z, 0.f); v.w = fmaxf(v.w, 0.f);
            }
            us4 h4, l4;
            h4.x = f2bf(v.x); l4.x = f2bf(v.x - bf2f(h4.x));
            h4.y = f2bf(v.y); l4.y = f2bf(v.y - bf2f(h4.y));
            h4.z = f2bf(v.z); l4.z = f2bf(v.z - bf2f(h4.z));
            h4.w = f2bf(v.w); l4.w = f2bf(v.w - bf2f(h4.w));
            *(us4*)&Ah[r * LDA + kc] = h4;
            *(us4*)&Al[r * LDA + kc] = l4;
        }
        // ---- stage B^T: 128 rows(n) x 32 k, 16B per thread per plane, 2 passes ----
#pragma unroll
        for (int p = 0; p < 2; p++) {
            int i = p * 256 + tid;            // 0..511 short8 chunks
            int nn = i >> 2;                  // 0..127
            int kc = (i & 3) * 8;             // 0,8,16,24
            size_t gidx = (size_t)(col0 + nn) * Kp + k0 + kc;
            *(short8*)&Bh[nn * LDA + kc] = *(const short8*)&WhT[gidx];
            *(short8*)&Bl[nn * LDA + kc] = *(const short8*)&WlT[gidx];
        }
        __syncthreads();

        // ---- fragments + MFMA: 2 m-frags x 4 n-frags x 3 terms = 24 MFMA ----
        short8 ah[2], al[2];
#pragma unroll
        for (int b = 0; b < 2; b++) {
            int off = (rh + b * 16 + l16) * LDA + quad * 8;
            ah[b] = *(const short8*)&Ah[off];
            al[b] = *(const short8*)&Al[off];
        }
#pragma unroll
        for (int ct = 0; ct < 4; ct++) {
            int off = (ch + ct * 16 + l16) * LDA + quad * 8;
            short8 bh = *(const short8*)&Bh[off];
            short8 bl = *(const short8*)&Bl[off];
#pragma unroll
            for (int b = 0; b < 2; b++) {
                acc[b][ct] = __builtin_amdgcn_mfma_f32_16x16x32_bf16(ah[b], bh, acc[b][ct], 0, 0, 0);
                acc[b][ct] = __builtin_amdgcn_mfma_f32_16x16x32_bf16(ah[b], bl, acc[b][ct], 0, 0, 0);
                acc[b][ct] = __builtin_amdgcn_mfma_f32_16x16x32_bf16(al[b], bh, acc[b][ct], 0, 0, 0);
            }
        }
        __syncthreads();
    }

    // ---- epilogue: C/D layout col=lane&15, row=quad*4+reg ----
#pragma unroll
    for (int b = 0; b < 2; b++) {
#pragma unroll
        for (int ct = 0; ct < 4; ct++) {
            int gc = col0 + ch + ct * 16 + l16;
#pragma unroll
            for (int r = 0; r < 4; r++) {
                int gr = row0 + rh + b * 16 + quad * 4 + r;
                if (gr < M) C[(size_t)gr * N + gc] = acc[b][ct][r];
            }
        }
    }
}

// ---------------- gather aggregation, F=512 ----------------

__global__ __launch_bounds__(256) void gather512_kernel(
    const float* __restrict__ h, float* __restrict__ out,
    const int* __restrict__ csr_src, const int* __restrict__ row_start,
    const float* __restrict__ dinv, const float* __restrict__ bias, int n)
{
    const int node = blockIdx.x;
    const int f = threadIdx.x;
    const float di = dinv[node];

    const size_t base = (size_t)node * 512;
    float acc0 = h[base + f] * di * di + bias[f];
    float acc1 = h[base + f + 256] * di * di + bias[f + 256];

    const int beg = row_start[node], end = row_start[node + 1];
    for (int p = beg; p < end; ++p) {
        int s = csr_src[p];
        float w = dinv[s] * di;
        const size_t sb = (size_t)s * 512;
        acc0 += h[sb + f] * w;
        acc1 += h[sb + f + 256] * w;
    }
    out[base + f] = acc0;
    out[base + f + 256] = acc1;
}

// ---------------- gather aggregation, F=10 ----------------

__global__ void gather10_kernel(
    const float* __restrict__ h, float* __restrict__ out,
    const int* __restrict__ csr_src, const int* __restrict__ row_start,
    const float* __restrict__ dinv, const float* __restrict__ bias, int n)
{
    int idx = blockIdx.x * blockDim.x + threadIdx.x;
    if (idx >= n * 10) return;
    int node = idx / 10;
    int c = idx % 10;
    float di = dinv[node];
    float acc = h[(size_t)node * 10 + c] * di * di + bias[c];
    int beg = row_start[node], end = row_start[node + 1];
    for (int p = beg; p < end; ++p) {
        int s = csr_src[p];
        acc += h[(size_t)s * 10 + c] * dinv[s] * di;
    }
    out[idx] = acc;
}

// ---------------- small GEMM: C[M,10] = relu(A[M,512]) @ W[512,10] ----------------

__global__ __launch_bounds__(256) void gemm_small_kernel(
    const float* __restrict__ A, const float* __restrict__ W, float* __restrict__ C,
    int M, int K, int relu_a)
{
    __shared__ float Ws[512 * 10];
    for (int i = threadIdx.x; i < K * 10; i += blockDim.x) Ws[i] = W[i];
    __syncthreads();

    const int wave = threadIdx.x >> 6;
    const int lane = threadIdx.x & 63;
    const int row = blockIdx.x * (blockDim.x >> 6) + wave;
    if (row >= M) return;

    float acc[10];
#pragma unroll
    for (int c = 0; c < 10; c++) acc[c] = 0.f;

    for (int k = lane; k < K; k += 64) {
        float a = A[(size_t)row * K + k];
        if (relu_a) a = fmaxf(a, 0.f);
#pragma unroll
        for (int c = 0; c < 10; c++) acc[c] += a * Ws[k * 10 + c];
    }
#pragma unroll
    for (int c = 0; c < 10; c++) {
#pragma unroll
        for (int off = 32; off; off >>= 1) acc[c] += __shfl_down(acc[c], off);
    }
    if (lane == 0) {
#pragma unroll
        for (int c = 0; c < 10; c++) C[(size_t)row * 10 + c] = acc[c];
    }
}

// ---------------- log_softmax over 10 classes ----------------

__global__ void logsoftmax10_kernel(const float* __restrict__ logits, float* __restrict__ out, int n)
{
    int i = blockIdx.x * blockDim.x + threadIdx.x;
    if (i >= n) return;
    float v[10];
    float m = -1e30f;
#pragma unroll
    for (int c = 0; c < 10; c++) { v[c] = logits[(size_t)i * 10 + c]; m = fmaxf(m, v[c]); }
    float s = 0.f;
#pragma unroll
    for (int c = 0; c < 10; c++) s += __expf(v[c] - m);
    float ls = m + __logf(s);
#pragma unroll
    for (int c = 0; c < 10; c++) out[(size_t)i * 10 + c] = v[c] - ls;
}

// ---------------- launch ----------------

extern "C" void kernel_launch(void* const* d_in, const int* in_sizes, int n_in,
                              void* d_out, int out_size, void* d_ws, size_t ws_size,
                              hipStream_t stream)
{
    const float* x   = (const float*)d_in[0];
    const int*   ei  = (const int*)d_in[1];
    const float* W1  = (const float*)d_in[2];
    const float* b1  = (const float*)d_in[3];
    const float* W2  = (const float*)d_in[4];
    const float* b2  = (const float*)d_in[5];
    const float* Wc  = (const float*)d_in[6];
    const float* bc  = (const float*)d_in[7];
    float* out = (float*)d_out;

    const int IN_FEATS = 784;
    const int KP1 = 800;                    // 784 padded to multiple of 32
    const int H = 512;
    const int NC = 10;
    const int n = in_sizes[0] / IN_FEATS;   // 10000
    const int E = in_sizes[1] / 2;          // 160000
    const int* src = ei;
    const int* dst = ei + E;

    // workspace layout (~43.4 MB)
    char* ws = (char*)d_ws;
    float* bufA      = (float*)ws;           ws += (size_t)n * H * sizeof(float);
    float* bufB      = (float*)ws;           ws += (size_t)n * H * sizeof(float);
    unsigned short* WhT = (unsigned short*)ws; ws += (size_t)KP1 * H * sizeof(unsigned short);
    unsigned short* WlT = (unsigned short*)ws; ws += (size_t)KP1 * H * sizeof(unsigned short);
    float* dinv      = (float*)ws;           ws += (size_t)n * sizeof(float);
    int*   deg       = (int*)ws;             ws += (size_t)n * sizeof(int);
    int*   cursor    = (int*)ws;             ws += (size_t)n * sizeof(int);
    int*   csr_src   = (int*)ws;             ws += (size_t)E * sizeof(int);
    int*   row_start = (int*)ws;             ws += (size_t)(n + 1) * sizeof(int);

    float* h3     = bufA;                    // layer-3 small buffers reuse bufA
    float* logits = bufA + (size_t)n * NC;

    // ---- CSR build + dinv ----
    hipMemsetAsync(deg, 0, (size_t)n * sizeof(int), stream);
    hipMemsetAsync(cursor, 0, (size_t)n * sizeof(int), stream);
    count_deg_kernel<<<(E + 255) / 256, 256, 0, stream>>>(dst, deg, E);
    scan_kernel<<<1, 256, 0, stream>>>(deg, row_start, dinv, n);
    fill_csr_kernel<<<(E + 255) / 256, 256, 0, stream>>>(src, dst, row_start, cursor, csr_src, E);

    const int tiles_m = (n + TBM - 1) / TBM;       // 157
    const int tiles_n = H / TBN;                   // 4
    const int gemm_grid = tiles_m * tiles_n;       // 628

    // ---- layer 1: h1 = x @ W1 ; agg1 = gather(h1) ----
    convW_kernel<<<(H * KP1 + 255) / 256, 256, 0, stream>>>(W1, WhT, WlT, IN_FEATS, H, KP1);
    gemm_mfma_kernel<<<gemm_grid, 256, 0, stream>>>(x, WhT, WlT, bufA, n, H, IN_FEATS, KP1, tiles_m, 0);
    gather512_kernel<<<n, 256, 0, stream>>>(bufA, bufB, csr_src, row_start, dinv, b1, n);

    // ---- layer 2: h2 = relu(agg1) @ W2 ; agg2 = gather(h2) ----
    convW_kernel<<<(H * H + 255) / 256, 256, 0, stream>>>(W2, WhT, WlT, H, H, H);
    gemm_mfma_kernel<<<gemm_grid, 256, 0, stream>>>(bufB, WhT, WlT, bufA, n, H, H, H, tiles_m, 1);
    gather512_kernel<<<n, 256, 0, stream>>>(bufA, bufB, csr_src, row_start, dinv, b2, n);

    // ---- layer 3: h3 = relu(agg2) @ Wc ; logits = gather(h3) ----
    gemm_small_kernel<<<(n + 3) / 4, 256, 0, stream>>>(bufB, Wc, h3, n, H, 1);
    gather10_kernel<<<(n * NC + 255) / 256, 256, 0, stream>>>(h3, logits, csr_src, row_start, dinv, bc, n);

    // ---- log_softmax ----
    logsoftmax10_kernel<<<(n + 255) / 256, 256, 0, stream>>>(logits, out, n);
}

// Round 5
// 360.024 us; speedup vs baseline: 7.2692x; 1.0859x over previous
//
#include <hip/hip_runtime.h>
#include <hip/hip_bf16.h>
#include <math.h>

typedef __attribute__((ext_vector_type(8))) short short8;
typedef __attribute__((ext_vector_type(4))) float f32x4;
typedef __attribute__((ext_vector_type(4))) unsigned short us4;

__device__ inline unsigned short f2bf(float f) {
    unsigned int u = __float_as_uint(f);
    unsigned int r = u + 0x7fffu + ((u >> 16) & 1u);   // RTNE
    return (unsigned short)(r >> 16);
}
__device__ inline float bf2f(unsigned short h) {
    return __uint_as_float(((unsigned int)h) << 16);
}

// ---------------- degree count ----------------

__global__ void count_deg_kernel(const int* __restrict__ dst, int* __restrict__ deg, int E) {
    int e = blockIdx.x * blockDim.x + threadIdx.x;
    if (e < E) atomicAdd(&deg[dst[e]], 1);
}

// ---------------- one-block scan -> row_start; also dinv (shuffle-based) ----------------

__global__ __launch_bounds__(256) void scan_kernel(const int* __restrict__ deg,
                                                   int* __restrict__ row_start,
                                                   float* __restrict__ dinv, int n)
{
    __shared__ int swave[4];
    const int lane = threadIdx.x & 63;
    const int w = threadIdx.x >> 6;
    int running = 0;

    for (int base = 0; base < n; base += 256) {
        int i = base + threadIdx.x;
        int v = (i < n) ? deg[i] : 0;
        int incl = v;
#pragma unroll
        for (int off = 1; off < 64; off <<= 1) {
            int t = __shfl_up(incl, off);
            if (lane >= off) incl += t;
        }
        if (lane == 63) swave[w] = incl;
        __syncthreads();
        int wpre = 0;
#pragma unroll
        for (int j = 0; j < 4; j++) if (j < w) wpre += swave[j];
        int total = swave[0] + swave[1] + swave[2] + swave[3];
        if (i < n) {
            row_start[i] = running + wpre + incl - v;
            dinv[i] = rsqrtf((float)v + 1.0f);
        }
        running += total;
        __syncthreads();
    }
    if (threadIdx.x == 0) row_start[n] = running;
}

// ---------------- CSR fill ----------------

__global__ void fill_csr_kernel(const int* __restrict__ src, const int* __restrict__ dst,
                                const int* __restrict__ row_start, int* __restrict__ cursor,
                                int* __restrict__ csr_src, int E)
{
    int e = blockIdx.x * blockDim.x + threadIdx.x;
    if (e >= E) return;
    int d = dst[e];
    int pos = row_start[d] + atomicAdd(&cursor[d], 1);
    csr_src[pos] = src[e];
}

// ---------------- W split+transpose: W[K,N] fp32 -> WhT/WlT [N,Kp] bf16 (zero-padded) ----------------

__global__ void convW_kernel(const float* __restrict__ W,
                             unsigned short* __restrict__ WhT, unsigned short* __restrict__ WlT,
                             int K, int N, int Kp)
{
    int id = blockIdx.x * blockDim.x + threadIdx.x;
    if (id >= N * Kp) return;
    int nrow = id / Kp;
    int k = id - nrow * Kp;
    float v = (k < K) ? W[(size_t)k * N + nrow] : 0.f;
    unsigned short h = f2bf(v);
    WhT[id] = h;
    WlT[id] = f2bf(v - bf2f(h));
}

// ---------------- X split: x[n,784] fp32 -> Xh/Xl [n,800] bf16 (k-padded) ----------------

__global__ void convX_kernel(const float* __restrict__ X,
                             unsigned short* __restrict__ Xh, unsigned short* __restrict__ Xl,
                             int M, int K, int Kp)
{
    int id = blockIdx.x * blockDim.x + threadIdx.x;
    if (id >= M * Kp) return;
    int r = id / Kp;
    int k = id - r * Kp;
    float v = (k < K) ? X[(size_t)r * K + k] : 0.f;
    unsigned short h = f2bf(v);
    Xh[id] = h;
    Xl[id] = f2bf(v - bf2f(h));
}

// ---------------- MFMA GEMM: C[M,N] = A @ W, 3-term bf16 split, A pre-split into hi/lo planes ----
// Tile 128x128, BK=32, 256 threads (4 waves, 2x2), LDS rows padded to 40 shorts.

#define TBM 128
#define TBN 128
#define TBK 32
#define LDA (TBK + 8)

__global__ __launch_bounds__(256) void gemm_mfma_kernel(
    const unsigned short* __restrict__ AhG, const unsigned short* __restrict__ AlG,
    const unsigned short* __restrict__ WhT, const unsigned short* __restrict__ WlT,
    float* __restrict__ C, int M, int N, int Kp, int tiles_m)
{
    __shared__ unsigned short Ah[TBM * LDA];
    __shared__ unsigned short Al[TBM * LDA];
    __shared__ unsigned short Bh[TBN * LDA];
    __shared__ unsigned short Bl[TBN * LDA];

    const int tid = threadIdx.x;
    const int g = blockIdx.x;
    const int tn = g & 3;                // 4 consecutive blocks share the same A tile -> L3 hits
    const int tm = g >> 2;
    const int row0 = tm * TBM;
    const int col0 = tn * TBN;

    const int wave = tid >> 6;
    const int lane = tid & 63;
    const int quad = lane >> 4;
    const int l16  = lane & 15;
    const int rh = (wave & 1) * 64;      // wave row-half
    const int ch = (wave >> 1) * 64;     // wave col-half

    f32x4 acc[4][4];
#pragma unroll
    for (int b = 0; b < 4; b++)
#pragma unroll
        for (int c = 0; c < 4; c++) acc[b][c] = (f32x4){0.f, 0.f, 0.f, 0.f};

    for (int k0 = 0; k0 < Kp; k0 += TBK) {
        // ---- stage A: 128 rows x 32 k bf16, hi+lo, short8 per thread x2 ----
#pragma unroll
        for (int p = 0; p < 2; p++) {
            int i = p * 256 + tid;            // 0..511
            int r = i >> 2;                   // 0..127
            int kc = (i & 3) * 8;             // 0,8,16,24
            int gr = row0 + r; if (gr >= M) gr = M - 1;   // clamp (rows >= M never stored)
            size_t gidx = (size_t)gr * Kp + k0 + kc;
            *(short8*)&Ah[r * LDA + kc] = *(const short8*)&AhG[gidx];
            *(short8*)&Al[r * LDA + kc] = *(const short8*)&AlG[gidx];
        }
        // ---- stage B^T: 128 n-rows x 32 k ----
#pragma unroll
        for (int p = 0; p < 2; p++) {
            int i = p * 256 + tid;
            int nn = i >> 2;
            int kc = (i & 3) * 8;
            size_t gidx = (size_t)(col0 + nn) * Kp + k0 + kc;
            *(short8*)&Bh[nn * LDA + kc] = *(const short8*)&WhT[gidx];
            *(short8*)&Bl[nn * LDA + kc] = *(const short8*)&WlT[gidx];
        }
        __syncthreads();

        // ---- fragments + MFMA: 4 m-frags x 4 n-frags x 3 terms = 48 MFMA/wave ----
        short8 ah[4], al[4];
#pragma unroll
        for (int b = 0; b < 4; b++) {
            int off = (rh + b * 16 + l16) * LDA + quad * 8;
            ah[b] = *(const short8*)&Ah[off];
            al[b] = *(const short8*)&Al[off];
        }
#pragma unroll
        for (int ct = 0; ct < 4; ct++) {
            int off = (ch + ct * 16 + l16) * LDA + quad * 8;
            short8 bh = *(const short8*)&Bh[off];
            short8 bl = *(const short8*)&Bl[off];
#pragma unroll
            for (int b = 0; b < 4; b++) {
                acc[b][ct] = __builtin_amdgcn_mfma_f32_16x16x32_bf16(ah[b], bh, acc[b][ct], 0, 0, 0);
                acc[b][ct] = __builtin_amdgcn_mfma_f32_16x16x32_bf16(ah[b], bl, acc[b][ct], 0, 0, 0);
                acc[b][ct] = __builtin_amdgcn_mfma_f32_16x16x32_bf16(al[b], bh, acc[b][ct], 0, 0, 0);
            }
        }
        __syncthreads();
    }

    // ---- epilogue: C/D layout col=lane&15, row=quad*4+reg ----
#pragma unroll
    for (int b = 0; b < 4; b++) {
#pragma unroll
        for (int ct = 0; ct < 4; ct++) {
            int gc = col0 + ch + ct * 16 + l16;
#pragma unroll
            for (int r = 0; r < 4; r++) {
                int gr = row0 + rh + b * 16 + quad * 4 + r;
                if (gr < M) C[(size_t)gr * N + gc] = acc[b][ct][r];
            }
        }
    }
}

// ---------------- gather aggregation, F=512; emits relu'd hi/lo bf16 planes ----------------
// agg[i] = sum_{e: dst=i} h[src]*dinv[src]*dinv[i] + h[i]*dinv[i]^2 + bias; out = split(relu(agg))

__global__ __launch_bounds__(256) void gather512_kernel(
    const float* __restrict__ h,
    unsigned short* __restrict__ out_h, unsigned short* __restrict__ out_l,
    const int* __restrict__ csr_src, const int* __restrict__ row_start,
    const float* __restrict__ dinv, const float* __restrict__ bias, int n)
{
    const int node = blockIdx.x;
    const int t = threadIdx.x;            // float2 index: features 2t, 2t+1
    const float di = dinv[node];

    const float2* h2 = (const float2*)h;
    const size_t base2 = (size_t)node * 256;

    float2 b2 = ((const float2*)bias)[t];
    float2 v0 = h2[base2 + t];
    float dd = di * di;
    float accx = v0.x * dd + b2.x;
    float accy = v0.y * dd + b2.y;

    const int beg = row_start[node], end = row_start[node + 1];
    for (int p = beg; p < end; ++p) {
        int s = csr_src[p];
        float w = dinv[s] * di;
        float2 v = h2[(size_t)s * 256 + t];
        accx += v.x * w;
        accy += v.y * w;
    }
    accx = fmaxf(accx, 0.f);
    accy = fmaxf(accy, 0.f);
    unsigned short hx = f2bf(accx), hy = f2bf(accy);
    ushort2 ho, lo;
    ho.x = hx; ho.y = hy;
    lo.x = f2bf(accx - bf2f(hx)); lo.y = f2bf(accy - bf2f(hy));
    ((ushort2*)out_h)[base2 + t] = ho;
    ((ushort2*)out_l)[base2 + t] = lo;
}

// ---------------- gather aggregation, F=10 (no relu) ----------------

__global__ void gather10_kernel(
    const float* __restrict__ h, float* __restrict__ out,
    const int* __restrict__ csr_src, const int* __restrict__ row_start,
    const float* __restrict__ dinv, const float* __restrict__ bias, int n)
{
    int idx = blockIdx.x * blockDim.x + threadIdx.x;
    if (idx >= n * 10) return;
    int node = idx / 10;
    int c = idx % 10;
    float di = dinv[node];
    float acc = h[(size_t)node * 10 + c] * di * di + bias[c];
    int beg = row_start[node], end = row_start[node + 1];
    for (int p = beg; p < end; ++p) {
        int s = csr_src[p];
        acc += h[(size_t)s * 10 + c] * dinv[s] * di;
    }
    out[idx] = acc;
}

// ---------------- small GEMM: C[M,10] = A[M,512] @ W[512,10], A given as hi/lo bf16 planes ----------------

__global__ __launch_bounds__(256) void gemm_small_kernel(
    const unsigned short* __restrict__ Ahp, const unsigned short* __restrict__ Alp,
    const float* __restrict__ W, float* __restrict__ C, int M, int K)
{
    __shared__ float Ws[512 * 10];
    for (int i = threadIdx.x; i < K * 10; i += blockDim.x) Ws[i] = W[i];
    __syncthreads();

    const int wave = threadIdx.x >> 6;
    const int lane = threadIdx.x & 63;
    const int row = blockIdx.x * (blockDim.x >> 6) + wave;
    if (row >= M) return;

    float acc[10];
#pragma unroll
    for (int c = 0; c < 10; c++) acc[c] = 0.f;

    for (int k = lane; k < K; k += 64) {
        float a = bf2f(Ahp[(size_t)row * K + k]) + bf2f(Alp[(size_t)row * K + k]);
#pragma unroll
        for (int c = 0; c < 10; c++) acc[c] += a * Ws[k * 10 + c];
    }
#pragma unroll
    for (int c = 0; c < 10; c++) {
#pragma unroll
        for (int off = 32; off; off >>= 1) acc[c] += __shfl_down(acc[c], off);
    }
    if (lane == 0) {
#pragma unroll
        for (int c = 0; c < 10; c++) C[(size_t)row * 10 + c] = acc[c];
    }
}

// ---------------- log_softmax over 10 classes ----------------

__global__ void logsoftmax10_kernel(const float* __restrict__ logits, float* __restrict__ out, int n)
{
    int i = blockIdx.x * blockDim.x + threadIdx.x;
    if (i >= n) return;
    float v[10];
    float m = -1e30f;
#pragma unroll
    for (int c = 0; c < 10; c++) { v[c] = logits[(size_t)i * 10 + c]; m = fmaxf(m, v[c]); }
    float s = 0.f;
#pragma unroll
    for (int c = 0; c < 10; c++) s += __expf(v[c] - m);
    float ls = m + __logf(s);
#pragma unroll
    for (int c = 0; c < 10; c++) out[(size_t)i * 10 + c] = v[c] - ls;
}

// ---------------- launch ----------------

extern "C" void kernel_launch(void* const* d_in, const int* in_sizes, int n_in,
                              void* d_out, int out_size, void* d_ws, size_t ws_size,
                              hipStream_t stream)
{
    const float* x   = (const float*)d_in[0];
    const int*   ei  = (const int*)d_in[1];
    const float* W1  = (const float*)d_in[2];
    const float* b1  = (const float*)d_in[3];
    const float* W2  = (const float*)d_in[4];
    const float* b2  = (const float*)d_in[5];
    const float* Wc  = (const float*)d_in[6];
    const float* bc  = (const float*)d_in[7];
    float* out = (float*)d_out;

    const int IN_FEATS = 784;
    const int KP1 = 800;                    // padded K for layer 1
    const int H = 512;
    const int NC = 10;
    const int n = in_sizes[0] / IN_FEATS;   // 10000
    const int E = in_sizes[1] / 2;          // 160000
    const int* src = ei;
    const int* dst = ei + E;

    // workspace layout (~76 MB)
    char* ws = (char*)d_ws;
    float* bufH      = (float*)ws;             ws += (size_t)n * H * sizeof(float);            // 20.48 MB  (h1/h2)
    unsigned short* Xh  = (unsigned short*)ws; ws += (size_t)n * KP1 * sizeof(unsigned short); // 16 MB
    unsigned short* Xl  = (unsigned short*)ws; ws += (size_t)n * KP1 * sizeof(unsigned short); // 16 MB
    unsigned short* AhB = (unsigned short*)ws; ws += (size_t)n * H * sizeof(unsigned short);   // 10.24 MB
    unsigned short* AlB = (unsigned short*)ws; ws += (size_t)n * H * sizeof(unsigned short);   // 10.24 MB
    unsigned short* WhT = (unsigned short*)ws; ws += (size_t)KP1 * H * sizeof(unsigned short); // 0.82 MB
    unsigned short* WlT = (unsigned short*)ws; ws += (size_t)KP1 * H * sizeof(unsigned short); // 0.82 MB
    float* dinv      = (float*)ws;             ws += (size_t)n * sizeof(float);
    int*   deg       = (int*)ws;               ws += (size_t)n * sizeof(int);
    int*   cursor    = (int*)ws;               ws += (size_t)n * sizeof(int);
    int*   csr_src   = (int*)ws;               ws += (size_t)E * sizeof(int);
    int*   row_start = (int*)ws;               ws += (size_t)(n + 1) * sizeof(int);
    float* h3        = (float*)ws;             ws += (size_t)n * NC * sizeof(float);
    float* logits    = (float*)ws;             ws += (size_t)n * NC * sizeof(float);

    // ---- CSR build + dinv ----
    hipMemsetAsync(deg, 0, (size_t)n * sizeof(int), stream);
    hipMemsetAsync(cursor, 0, (size_t)n * sizeof(int), stream);
    count_deg_kernel<<<(E + 255) / 256, 256, 0, stream>>>(dst, deg, E);
    scan_kernel<<<1, 256, 0, stream>>>(deg, row_start, dinv, n);
    fill_csr_kernel<<<(E + 255) / 256, 256, 0, stream>>>(src, dst, row_start, cursor, csr_src, E);

    const int tiles_m = (n + TBM - 1) / TBM;       // 79
    const int gemm_grid = tiles_m * (H / TBN);     // 79*4 = 316

    // ---- input conversions ----
    convX_kernel<<<((size_t)n * KP1 + 255) / 256, 256, 0, stream>>>(x, Xh, Xl, n, IN_FEATS, KP1);
    convW_kernel<<<(H * KP1 + 255) / 256, 256, 0, stream>>>(W1, WhT, WlT, IN_FEATS, H, KP1);

    // ---- layer 1: h1 = x @ W1 ; (AhB,AlB) = split(relu(gather(h1))) ----
    gemm_mfma_kernel<<<gemm_grid, 256, 0, stream>>>(Xh, Xl, WhT, WlT, bufH, n, H, KP1, tiles_m);
    gather512_kernel<<<n, 256, 0, stream>>>(bufH, AhB, AlB, csr_src, row_start, dinv, b1, n);

    // ---- layer 2: h2 = (AhB+AlB) @ W2 ; (AhB,AlB) = split(relu(gather(h2))) ----
    convW_kernel<<<(H * H + 255) / 256, 256, 0, stream>>>(W2, WhT, WlT, H, H, H);
    gemm_mfma_kernel<<<gemm_grid, 256, 0, stream>>>(AhB, AlB, WhT, WlT, bufH, n, H, H, tiles_m);
    gather512_kernel<<<n, 256, 0, stream>>>(bufH, AhB, AlB, csr_src, row_start, dinv, b2, n);

    // ---- layer 3: h3 = (AhB+AlB) @ Wc ; logits = gather(h3) ----
    gemm_small_kernel<<<(n + 3) / 4, 256, 0, stream>>>(AhB, AlB, Wc, h3, n, H);
    gather10_kernel<<<(n * NC + 255) / 256, 256, 0, stream>>>(h3, logits, csr_src, row_start, dinv, bc, n);

    // ---- log_softmax ----
    logsoftmax10_kernel<<<(n + 255) / 256, 256, 0, stream>>>(logits, out, n);
}

// Round 6
// 346.144 us; speedup vs baseline: 7.5607x; 1.0401x over previous
//
#include <hip/hip_runtime.h>
#include <hip/hip_bf16.h>
#include <math.h>

typedef __attribute__((ext_vector_type(8))) short short8;
typedef __attribute__((ext_vector_type(4))) float f32x4;

__device__ inline unsigned short f2bf(float f) {
    unsigned int u = __float_as_uint(f);
    unsigned int r = u + 0x7fffu + ((u >> 16) & 1u);   // RTNE
    return (unsigned short)(r >> 16);
}
__device__ inline float bf2f(unsigned short h) {
    return __uint_as_float(((unsigned int)h) << 16);
}

// ---------------- degree count ----------------

__global__ void count_deg_kernel(const int* __restrict__ dst, int* __restrict__ deg, int E) {
    int e = blockIdx.x * blockDim.x + threadIdx.x;
    if (e < E) atomicAdd(&deg[dst[e]], 1);
}

// ---------------- one-block scan -> row_start; also dinv (shuffle-based) ----------------

__global__ __launch_bounds__(256) void scan_kernel(const int* __restrict__ deg,
                                                   int* __restrict__ row_start,
                                                   float* __restrict__ dinv, int n)
{
    __shared__ int swave[4];
    const int lane = threadIdx.x & 63;
    const int w = threadIdx.x >> 6;
    int running = 0;

    for (int base = 0; base < n; base += 256) {
        int i = base + threadIdx.x;
        int v = (i < n) ? deg[i] : 0;
        int incl = v;
#pragma unroll
        for (int off = 1; off < 64; off <<= 1) {
            int t = __shfl_up(incl, off);
            if (lane >= off) incl += t;
        }
        if (lane == 63) swave[w] = incl;
        __syncthreads();
        int wpre = 0;
#pragma unroll
        for (int j = 0; j < 4; j++) if (j < w) wpre += swave[j];
        int total = swave[0] + swave[1] + swave[2] + swave[3];
        if (i < n) {
            row_start[i] = running + wpre + incl - v;
            dinv[i] = rsqrtf((float)v + 1.0f);
        }
        running += total;
        __syncthreads();
    }
    if (threadIdx.x == 0) row_start[n] = running;
}

// ---------------- CSR fill ----------------

__global__ void fill_csr_kernel(const int* __restrict__ src, const int* __restrict__ dst,
                                const int* __restrict__ row_start, int* __restrict__ cursor,
                                int* __restrict__ csr_src, int E)
{
    int e = blockIdx.x * blockDim.x + threadIdx.x;
    if (e >= E) return;
    int d = dst[e];
    int pos = row_start[d] + atomicAdd(&cursor[d], 1);
    csr_src[pos] = src[e];
}

// ---------------- W split+transpose: W[K,N] fp32 -> WhT/WlT [N,Kp] bf16 (zero-padded) ----------------

__global__ void convW_kernel(const float* __restrict__ W,
                             unsigned short* __restrict__ WhT, unsigned short* __restrict__ WlT,
                             int K, int N, int Kp)
{
    int id = blockIdx.x * blockDim.x + threadIdx.x;
    if (id >= N * Kp) return;
    int nrow = id / Kp;
    int k = id - nrow * Kp;
    float v = (k < K) ? W[(size_t)k * N + nrow] : 0.f;
    unsigned short h = f2bf(v);
    WhT[id] = h;
    WlT[id] = f2bf(v - bf2f(h));
}

// ---------------- X split: x[n,784] fp32 -> Xh/Xl [n,800] bf16 (k-padded) ----------------

__global__ void convX_kernel(const float* __restrict__ X,
                             unsigned short* __restrict__ Xh, unsigned short* __restrict__ Xl,
                             int M, int K, int Kp)
{
    int id = blockIdx.x * blockDim.x + threadIdx.x;
    if (id >= M * Kp) return;
    int r = id / Kp;
    int k = id - r * Kp;
    float v = (k < K) ? X[(size_t)r * K + k] : 0.f;
    unsigned short h = f2bf(v);
    Xh[id] = h;
    Xl[id] = f2bf(v - bf2f(h));
}

// ---------------- MFMA GEMM: C[M,N] = A @ W, 3-term bf16 split, A pre-split into hi/lo planes ----
// Tile 128x64, BK=32, 256 threads (4 waves, 2x2). 632 working blocks -> ~2.5 blocks/CU.
// XCD swizzle: the 8 blocks sharing an A row-tile have equal j%8 -> same XCD -> L2 sharing.

#define TBM 128
#define TBN 64
#define TBK 32
#define LDA (TBK + 8)

__global__ __launch_bounds__(256) void gemm_mfma_kernel(
    const unsigned short* __restrict__ AhG, const unsigned short* __restrict__ AlG,
    const unsigned short* __restrict__ WhT, const unsigned short* __restrict__ WlT,
    float* __restrict__ C, int M, int N, int Kp, int tiles_m)
{
    const int j = blockIdx.x;
    const int tn = (j >> 3) & 7;             // 0..7 column tile
    const int tm = (j >> 6) * 8 + (j & 7);   // row tile; same j%8 group shares tm on one XCD
    if (tm >= tiles_m) return;               // uniform block exit (padded grid)

    __shared__ unsigned short Ah[TBM * LDA];
    __shared__ unsigned short Al[TBM * LDA];
    __shared__ unsigned short Bh[TBN * LDA];
    __shared__ unsigned short Bl[TBN * LDA];

    const int tid = threadIdx.x;
    const int row0 = tm * TBM;
    const int col0 = tn * TBN;

    const int wave = tid >> 6;
    const int lane = tid & 63;
    const int quad = lane >> 4;
    const int l16  = lane & 15;
    const int rh = (wave & 1) * 64;      // wave row-half (64 rows)
    const int ch = (wave >> 1) * 32;     // wave col-half (32 cols)

    f32x4 acc[4][2];
#pragma unroll
    for (int b = 0; b < 4; b++)
#pragma unroll
        for (int c = 0; c < 2; c++) acc[b][c] = (f32x4){0.f, 0.f, 0.f, 0.f};

    for (int k0 = 0; k0 < Kp; k0 += TBK) {
        // ---- stage A: 128 rows x 32 k bf16, hi+lo, short8 per thread x2 ----
#pragma unroll
        for (int p = 0; p < 2; p++) {
            int i = p * 256 + tid;            // 0..511
            int r = i >> 2;                   // 0..127
            int kc = (i & 3) * 8;             // 0,8,16,24
            int gr = row0 + r; if (gr >= M) gr = M - 1;   // clamp (rows >= M never stored)
            size_t gidx = (size_t)gr * Kp + k0 + kc;
            *(short8*)&Ah[r * LDA + kc] = *(const short8*)&AhG[gidx];
            *(short8*)&Al[r * LDA + kc] = *(const short8*)&AlG[gidx];
        }
        // ---- stage B^T: 64 n-rows x 32 k ----
        {
            int nn = tid >> 2;                // 0..63
            int kc = (tid & 3) * 8;
            size_t gidx = (size_t)(col0 + nn) * Kp + k0 + kc;
            *(short8*)&Bh[nn * LDA + kc] = *(const short8*)&WhT[gidx];
            *(short8*)&Bl[nn * LDA + kc] = *(const short8*)&WlT[gidx];
        }
        __syncthreads();

        // ---- fragments + MFMA: 4 m-frags x 2 n-frags x 3 terms = 24 MFMA/wave ----
        short8 ah[4], al[4];
#pragma unroll
        for (int b = 0; b < 4; b++) {
            int off = (rh + b * 16 + l16) * LDA + quad * 8;
            ah[b] = *(const short8*)&Ah[off];
            al[b] = *(const short8*)&Al[off];
        }
#pragma unroll
        for (int ct = 0; ct < 2; ct++) {
            int off = (ch + ct * 16 + l16) * LDA + quad * 8;
            short8 bh = *(const short8*)&Bh[off];
            short8 bl = *(const short8*)&Bl[off];
#pragma unroll
            for (int b = 0; b < 4; b++) {
                acc[b][ct] = __builtin_amdgcn_mfma_f32_16x16x32_bf16(ah[b], bh, acc[b][ct], 0, 0, 0);
                acc[b][ct] = __builtin_amdgcn_mfma_f32_16x16x32_bf16(ah[b], bl, acc[b][ct], 0, 0, 0);
                acc[b][ct] = __builtin_amdgcn_mfma_f32_16x16x32_bf16(al[b], bh, acc[b][ct], 0, 0, 0);
            }
        }
        __syncthreads();
    }

    // ---- epilogue: C/D layout col=lane&15, row=quad*4+reg ----
#pragma unroll
    for (int b = 0; b < 4; b++) {
#pragma unroll
        for (int ct = 0; ct < 2; ct++) {
            int gc = col0 + ch + ct * 16 + l16;
#pragma unroll
            for (int r = 0; r < 4; r++) {
                int gr = row0 + rh + b * 16 + quad * 4 + r;
                if (gr < M) C[(size_t)gr * N + gc] = acc[b][ct][r];
            }
        }
    }
}

// ---------------- gather aggregation, F=512; emits relu'd hi/lo bf16 planes ----------------

__global__ __launch_bounds__(256) void gather512_kernel(
    const float* __restrict__ h,
    unsigned short* __restrict__ out_h, unsigned short* __restrict__ out_l,
    const int* __restrict__ csr_src, const int* __restrict__ row_start,
    const float* __restrict__ dinv, const float* __restrict__ bias, int n)
{
    const int node = blockIdx.x;
    const int t = threadIdx.x;            // float2 index: features 2t, 2t+1
    const float di = dinv[node];

    const float2* h2 = (const float2*)h;
    const size_t base2 = (size_t)node * 256;

    float2 b2 = ((const float2*)bias)[t];
    float2 v0 = h2[base2 + t];
    float dd = di * di;
    float accx = v0.x * dd + b2.x;
    float accy = v0.y * dd + b2.y;

    const int beg = row_start[node], end = row_start[node + 1];
    for (int p = beg; p < end; ++p) {
        int s = csr_src[p];
        float w = dinv[s] * di;
        float2 v = h2[(size_t)s * 256 + t];
        accx += v.x * w;
        accy += v.y * w;
    }
    accx = fmaxf(accx, 0.f);
    accy = fmaxf(accy, 0.f);
    unsigned short hx = f2bf(accx), hy = f2bf(accy);
    ushort2 ho, lo;
    ho.x = hx; ho.y = hy;
    lo.x = f2bf(accx - bf2f(hx)); lo.y = f2bf(accy - bf2f(hy));
    ((ushort2*)out_h)[base2 + t] = ho;
    ((ushort2*)out_l)[base2 + t] = lo;
}

// ---------------- gather aggregation, F=10 (no relu) ----------------

__global__ void gather10_kernel(
    const float* __restrict__ h, float* __restrict__ out,
    const int* __restrict__ csr_src, const int* __restrict__ row_start,
    const float* __restrict__ dinv, const float* __restrict__ bias, int n)
{
    int idx = blockIdx.x * blockDim.x + threadIdx.x;
    if (idx >= n * 10) return;
    int node = idx / 10;
    int c = idx % 10;
    float di = dinv[node];
    float acc = h[(size_t)node * 10 + c] * di * di + bias[c];
    int beg = row_start[node], end = row_start[node + 1];
    for (int p = beg; p < end; ++p) {
        int s = csr_src[p];
        acc += h[(size_t)s * 10 + c] * dinv[s] * di;
    }
    out[idx] = acc;
}

// ---------------- small GEMM: C[M,10] = A[M,512] @ W[512,10], A given as hi/lo bf16 planes ----------------

__global__ __launch_bounds__(256) void gemm_small_kernel(
    const unsigned short* __restrict__ Ahp, const unsigned short* __restrict__ Alp,
    const float* __restrict__ W, float* __restrict__ C, int M, int K)
{
    __shared__ float Ws[512 * 10];
    for (int i = threadIdx.x; i < K * 10; i += blockDim.x) Ws[i] = W[i];
    __syncthreads();

    const int wave = threadIdx.x >> 6;
    const int lane = threadIdx.x & 63;
    const int row = blockIdx.x * (blockDim.x >> 6) + wave;
    if (row >= M) return;

    float acc[10];
#pragma unroll
    for (int c = 0; c < 10; c++) acc[c] = 0.f;

    for (int k = lane; k < K; k += 64) {
        float a = bf2f(Ahp[(size_t)row * K + k]) + bf2f(Alp[(size_t)row * K + k]);
#pragma unroll
        for (int c = 0; c < 10; c++) acc[c] += a * Ws[k * 10 + c];
    }
#pragma unroll
    for (int c = 0; c < 10; c++) {
#pragma unroll
        for (int off = 32; off; off >>= 1) acc[c] += __shfl_down(acc[c], off);
    }
    if (lane == 0) {
#pragma unroll
        for (int c = 0; c < 10; c++) C[(size_t)row * 10 + c] = acc[c];
    }
}

// ---------------- log_softmax over 10 classes ----------------

__global__ void logsoftmax10_kernel(const float* __restrict__ logits, float* __restrict__ out, int n)
{
    int i = blockIdx.x * blockDim.x + threadIdx.x;
    if (i >= n) return;
    float v[10];
    float m = -1e30f;
#pragma unroll
    for (int c = 0; c < 10; c++) { v[c] = logits[(size_t)i * 10 + c]; m = fmaxf(m, v[c]); }
    float s = 0.f;
#pragma unroll
    for (int c = 0; c < 10; c++) s += __expf(v[c] - m);
    float ls = m + __logf(s);
#pragma unroll
    for (int c = 0; c < 10; c++) out[(size_t)i * 10 + c] = v[c] - ls;
}

// ---------------- launch ----------------

extern "C" void kernel_launch(void* const* d_in, const int* in_sizes, int n_in,
                              void* d_out, int out_size, void* d_ws, size_t ws_size,
                              hipStream_t stream)
{
    const float* x   = (const float*)d_in[0];
    const int*   ei  = (const int*)d_in[1];
    const float* W1  = (const float*)d_in[2];
    const float* b1  = (const float*)d_in[3];
    const float* W2  = (const float*)d_in[4];
    const float* b2  = (const float*)d_in[5];
    const float* Wc  = (const float*)d_in[6];
    const float* bc  = (const float*)d_in[7];
    float* out = (float*)d_out;

    const int IN_FEATS = 784;
    const int KP1 = 800;                    // padded K for layer 1
    const int H = 512;
    const int NC = 10;
    const int n = in_sizes[0] / IN_FEATS;   // 10000
    const int E = in_sizes[1] / 2;          // 160000
    const int* src = ei;
    const int* dst = ei + E;

    // workspace layout (~76 MB)
    char* ws = (char*)d_ws;
    float* bufH      = (float*)ws;             ws += (size_t)n * H * sizeof(float);            // 20.48 MB
    unsigned short* Xh  = (unsigned short*)ws; ws += (size_t)n * KP1 * sizeof(unsigned short); // 16 MB
    unsigned short* Xl  = (unsigned short*)ws; ws += (size_t)n * KP1 * sizeof(unsigned short); // 16 MB
    unsigned short* AhB = (unsigned short*)ws; ws += (size_t)n * H * sizeof(unsigned short);   // 10.24 MB
    unsigned short* AlB = (unsigned short*)ws; ws += (size_t)n * H * sizeof(unsigned short);   // 10.24 MB
    unsigned short* WhT = (unsigned short*)ws; ws += (size_t)KP1 * H * sizeof(unsigned short); // 0.82 MB
    unsigned short* WlT = (unsigned short*)ws; ws += (size_t)KP1 * H * sizeof(unsigned short); // 0.82 MB
    float* dinv      = (float*)ws;             ws += (size_t)n * sizeof(float);
    int*   deg       = (int*)ws;               ws += (size_t)n * sizeof(int);
    int*   cursor    = (int*)ws;               ws += (size_t)n * sizeof(int);
    int*   csr_src   = (int*)ws;               ws += (size_t)E * sizeof(int);
    int*   row_start = (int*)ws;               ws += (size_t)(n + 1) * sizeof(int);
    float* h3        = (float*)ws;             ws += (size_t)n * NC * sizeof(float);
    float* logits    = (float*)ws;             ws += (size_t)n * NC * sizeof(float);

    // ---- CSR build + dinv ----
    hipMemsetAsync(deg, 0, (size_t)n * sizeof(int), stream);
    hipMemsetAsync(cursor, 0, (size_t)n * sizeof(int), stream);
    count_deg_kernel<<<(E + 255) / 256, 256, 0, stream>>>(dst, deg, E);
    scan_kernel<<<1, 256, 0, stream>>>(deg, row_start, dinv, n);
    fill_csr_kernel<<<(E + 255) / 256, 256, 0, stream>>>(src, dst, row_start, cursor, csr_src, E);

    const int tiles_m = (n + TBM - 1) / TBM;                 // 79
    const int gemm_grid = ((tiles_m + 7) / 8) * 64;          // 10 groups * 64 = 640 (12 exit early)

    // ---- input conversions ----
    convX_kernel<<<((size_t)n * KP1 + 255) / 256, 256, 0, stream>>>(x, Xh, Xl, n, IN_FEATS, KP1);
    convW_kernel<<<(H * KP1 + 255) / 256, 256, 0, stream>>>(W1, WhT, WlT, IN_FEATS, H, KP1);

    // ---- layer 1: h1 = x @ W1 ; (AhB,AlB) = split(relu(gather(h1))) ----
    gemm_mfma_kernel<<<gemm_grid, 256, 0, stream>>>(Xh, Xl, WhT, WlT, bufH, n, H, KP1, tiles_m);
    gather512_kernel<<<n, 256, 0, stream>>>(bufH, AhB, AlB, csr_src, row_start, dinv, b1, n);

    // ---- layer 2: h2 = (AhB+AlB) @ W2 ; (AhB,AlB) = split(relu(gather(h2))) ----
    convW_kernel<<<(H * H + 255) / 256, 256, 0, stream>>>(W2, WhT, WlT, H, H, H);
    gemm_mfma_kernel<<<gemm_grid, 256, 0, stream>>>(AhB, AlB, WhT, WlT, bufH, n, H, H, tiles_m);
    gather512_kernel<<<n, 256, 0, stream>>>(bufH, AhB, AlB, csr_src, row_start, dinv, b2, n);

    // ---- layer 3: h3 = (AhB+AlB) @ Wc ; logits = gather(h3) ----
    gemm_small_kernel<<<(n + 3) / 4, 256, 0, stream>>>(AhB, AlB, Wc, h3, n, H);
    gather10_kernel<<<(n * NC + 255) / 256, 256, 0, stream>>>(h3, logits, csr_src, row_start, dinv, bc, n);

    // ---- log_softmax ----
    logsoftmax10_kernel<<<(n + 255) / 256, 256, 0, stream>>>(logits, out, n);
}

// Round 7
// 289.557 us; speedup vs baseline: 9.0382x; 1.1954x over previous
//
#include <hip/hip_runtime.h>
#include <hip/hip_bf16.h>
#include <math.h>

typedef __attribute__((ext_vector_type(8))) short short8;
typedef __attribute__((ext_vector_type(4))) float f32x4;

__device__ inline unsigned short f2bf(float f) {
    unsigned int u = __float_as_uint(f);
    unsigned int r = u + 0x7fffu + ((u >> 16) & 1u);   // RTNE
    return (unsigned short)(r >> 16);
}
__device__ inline float bf2f(unsigned short h) {
    return __uint_as_float(((unsigned int)h) << 16);
}

// ---------------- fused prep: convX + convW1 + convW2 + degree count ----------------

__global__ void prep_kernel(const float* __restrict__ x,
                            unsigned short* __restrict__ Xh, unsigned short* __restrict__ Xl,
                            const float* __restrict__ W1,
                            unsigned short* __restrict__ W1hT, unsigned short* __restrict__ W1lT,
                            const float* __restrict__ W2,
                            unsigned short* __restrict__ W2hT, unsigned short* __restrict__ W2lT,
                            const int* __restrict__ dst, int* __restrict__ deg,
                            int M, int K1, int Kp1, int H, int E,
                            int bX, int bW1, int bW2)
{
    const int b = blockIdx.x;
    const int tid = threadIdx.x;
    if (b < bX) {
        // X split: [M,K1] fp32 -> [M,Kp1] bf16 hi/lo
        int id = b * 256 + tid;
        if (id < M * Kp1) {
            int r = id / Kp1;
            int k = id - r * Kp1;
            float v = (k < K1) ? x[(size_t)r * K1 + k] : 0.f;
            unsigned short h = f2bf(v);
            Xh[id] = h;
            Xl[id] = f2bf(v - bf2f(h));
        }
    } else if (b < bX + bW1) {
        // W1 split+transpose: [K1,H] -> [H,Kp1]
        int id = (b - bX) * 256 + tid;
        if (id < H * Kp1) {
            int nrow = id / Kp1;
            int k = id - nrow * Kp1;
            float v = (k < K1) ? W1[(size_t)k * H + nrow] : 0.f;
            unsigned short h = f2bf(v);
            W1hT[id] = h;
            W1lT[id] = f2bf(v - bf2f(h));
        }
    } else if (b < bX + bW1 + bW2) {
        // W2 split+transpose: [H,H] -> [H,H]
        int id = (b - bX - bW1) * 256 + tid;
        if (id < H * H) {
            int nrow = id / H;
            int k = id - nrow * H;
            float v = W2[(size_t)k * H + nrow];
            unsigned short h = f2bf(v);
            W2hT[id] = h;
            W2lT[id] = f2bf(v - bf2f(h));
        }
    } else {
        // degree count
        int e = (b - bX - bW1 - bW2) * 256 + tid;
        if (e < E) atomicAdd(&deg[dst[e]], 1);
    }
}

// ---------------- one-block scan (1024 threads) -> row_start; also dinv ----------------

__global__ __launch_bounds__(1024) void scan_kernel(const int* __restrict__ deg,
                                                    int* __restrict__ row_start,
                                                    float* __restrict__ dinv, int n)
{
    __shared__ int swave[16];
    __shared__ int s_run;
    const int lane = threadIdx.x & 63;
    const int w = threadIdx.x >> 6;
    if (threadIdx.x == 0) s_run = 0;
    __syncthreads();

    for (int base = 0; base < n; base += 1024) {
        int i = base + threadIdx.x;
        int v = (i < n) ? deg[i] : 0;
        int incl = v;
#pragma unroll
        for (int off = 1; off < 64; off <<= 1) {
            int t = __shfl_up(incl, off);
            if (lane >= off) incl += t;
        }
        if (lane == 63) swave[w] = incl;
        __syncthreads();
        int wpre = 0, total = 0;
#pragma unroll
        for (int j = 0; j < 16; j++) {
            int sv = swave[j];
            if (j < w) wpre += sv;
            total += sv;
        }
        int run = s_run;
        if (i < n) {
            row_start[i] = run + wpre + incl - v;
            dinv[i] = rsqrtf((float)v + 1.0f);
        }
        __syncthreads();
        if (threadIdx.x == 0) s_run = run + total;
        __syncthreads();
    }
    if (threadIdx.x == 0) row_start[n] = s_run;
}

// ---------------- CSR fill ----------------

__global__ void fill_csr_kernel(const int* __restrict__ src, const int* __restrict__ dst,
                                const int* __restrict__ row_start, int* __restrict__ cursor,
                                int* __restrict__ csr_src, int E)
{
    int e = blockIdx.x * blockDim.x + threadIdx.x;
    if (e >= E) return;
    int d = dst[e];
    int pos = row_start[d] + atomicAdd(&cursor[d], 1);
    csr_src[pos] = src[e];
}

// ---------------- MFMA GEMM: Hb[M,N](bf16) = A @ W, 3-term bf16 split ----------------
// Tile 128x64, BK=32, 256 threads (4 waves). XCD swizzle: same j%8 shares A row-tile.

#define TBM 128
#define TBN 64
#define TBK 32
#define LDA (TBK + 8)

__global__ __launch_bounds__(256) void gemm_mfma_kernel(
    const unsigned short* __restrict__ AhG, const unsigned short* __restrict__ AlG,
    const unsigned short* __restrict__ WhT, const unsigned short* __restrict__ WlT,
    unsigned short* __restrict__ Hb, int M, int N, int Kp, int tiles_m)
{
    const int j = blockIdx.x;
    const int tn = (j >> 3) & 7;
    const int tm = (j >> 6) * 8 + (j & 7);
    if (tm >= tiles_m) return;

    __shared__ unsigned short Ah[TBM * LDA];
    __shared__ unsigned short Al[TBM * LDA];
    __shared__ unsigned short Bh[TBN * LDA];
    __shared__ unsigned short Bl[TBN * LDA];

    const int tid = threadIdx.x;
    const int row0 = tm * TBM;
    const int col0 = tn * TBN;

    const int wave = tid >> 6;
    const int lane = tid & 63;
    const int quad = lane >> 4;
    const int l16  = lane & 15;
    const int rh = (wave & 1) * 64;
    const int ch = (wave >> 1) * 32;

    f32x4 acc[4][2];
#pragma unroll
    for (int b = 0; b < 4; b++)
#pragma unroll
        for (int c = 0; c < 2; c++) acc[b][c] = (f32x4){0.f, 0.f, 0.f, 0.f};

    for (int k0 = 0; k0 < Kp; k0 += TBK) {
#pragma unroll
        for (int p = 0; p < 2; p++) {
            int i = p * 256 + tid;
            int r = i >> 2;
            int kc = (i & 3) * 8;
            int gr = row0 + r; if (gr >= M) gr = M - 1;
            size_t gidx = (size_t)gr * Kp + k0 + kc;
            *(short8*)&Ah[r * LDA + kc] = *(const short8*)&AhG[gidx];
            *(short8*)&Al[r * LDA + kc] = *(const short8*)&AlG[gidx];
        }
        {
            int nn = tid >> 2;
            int kc = (tid & 3) * 8;
            size_t gidx = (size_t)(col0 + nn) * Kp + k0 + kc;
            *(short8*)&Bh[nn * LDA + kc] = *(const short8*)&WhT[gidx];
            *(short8*)&Bl[nn * LDA + kc] = *(const short8*)&WlT[gidx];
        }
        __syncthreads();

        short8 ah[4], al[4];
#pragma unroll
        for (int b = 0; b < 4; b++) {
            int off = (rh + b * 16 + l16) * LDA + quad * 8;
            ah[b] = *(const short8*)&Ah[off];
            al[b] = *(const short8*)&Al[off];
        }
#pragma unroll
        for (int ct = 0; ct < 2; ct++) {
            int off = (ch + ct * 16 + l16) * LDA + quad * 8;
            short8 bh = *(const short8*)&Bh[off];
            short8 bl = *(const short8*)&Bl[off];
#pragma unroll
            for (int b = 0; b < 4; b++) {
                acc[b][ct] = __builtin_amdgcn_mfma_f32_16x16x32_bf16(ah[b], bh, acc[b][ct], 0, 0, 0);
                acc[b][ct] = __builtin_amdgcn_mfma_f32_16x16x32_bf16(ah[b], bl, acc[b][ct], 0, 0, 0);
                acc[b][ct] = __builtin_amdgcn_mfma_f32_16x16x32_bf16(al[b], bh, acc[b][ct], 0, 0, 0);
            }
        }
        __syncthreads();
    }

    // epilogue -> bf16 h
#pragma unroll
    for (int b = 0; b < 4; b++) {
#pragma unroll
        for (int ct = 0; ct < 2; ct++) {
            int gc = col0 + ch + ct * 16 + l16;
#pragma unroll
            for (int r = 0; r < 4; r++) {
                int gr = row0 + rh + b * 16 + quad * 4 + r;
                if (gr < M) Hb[(size_t)gr * N + gc] = f2bf(acc[b][ct][r]);
            }
        }
    }
}

// ---------------- gather aggregation, F=512, bf16 input; emits relu'd hi/lo bf16 planes ----------------
// Two half-blocks process even/odd edges (indices+weights staged in LDS) for 2x load ILP.

#define GMAX 1024

__global__ __launch_bounds__(256) void gather512_kernel(
    const unsigned short* __restrict__ hb,
    unsigned short* __restrict__ out_h, unsigned short* __restrict__ out_l,
    const int* __restrict__ csr_src, const int* __restrict__ row_start,
    const float* __restrict__ dinv, const float* __restrict__ bias, int n)
{
    __shared__ int   s_idx[GMAX];
    __shared__ float s_w[GMAX];
    __shared__ float s_part[512];

    const int node = blockIdx.x;
    const int tid = threadIdx.x;
    const int half = tid >> 7;       // 0,1
    const int slot = tid & 127;      // 4 features each
    const float di = dinv[node];

    const int beg = row_start[node], end = row_start[node + 1];

    float4 acc = make_float4(0.f, 0.f, 0.f, 0.f);

    for (int c0 = beg; c0 < end; c0 += GMAX) {
        int cnt = min(end - c0, GMAX);
        for (int p = tid; p < cnt; p += 256) {
            int s = csr_src[c0 + p];
            s_idx[p] = s;
            s_w[p] = dinv[s] * di;
        }
        __syncthreads();
        for (int p = half; p < cnt; p += 2) {
            int s = s_idx[p];
            float w = s_w[p];
            ushort4 r = *(const ushort4*)&hb[(size_t)s * 512 + slot * 4];
            acc.x += w * bf2f(r.x);
            acc.y += w * bf2f(r.y);
            acc.z += w * bf2f(r.z);
            acc.w += w * bf2f(r.w);
        }
        __syncthreads();
    }

    if (half == 1) *(float4*)&s_part[slot * 4] = acc;
    __syncthreads();
    if (half == 0) {
        float4 o = *(const float4*)&s_part[slot * 4];
        ushort4 rs = *(const ushort4*)&hb[(size_t)node * 512 + slot * 4];
        float4 b4 = *(const float4*)&bias[slot * 4];
        float dd = di * di;
        float vx = fmaxf(acc.x + o.x + dd * bf2f(rs.x) + b4.x, 0.f);
        float vy = fmaxf(acc.y + o.y + dd * bf2f(rs.y) + b4.y, 0.f);
        float vz = fmaxf(acc.z + o.z + dd * bf2f(rs.z) + b4.z, 0.f);
        float vw = fmaxf(acc.w + o.w + dd * bf2f(rs.w) + b4.w, 0.f);
        ushort4 ho, lo;
        ho.x = f2bf(vx); lo.x = f2bf(vx - bf2f(ho.x));
        ho.y = f2bf(vy); lo.y = f2bf(vy - bf2f(ho.y));
        ho.z = f2bf(vz); lo.z = f2bf(vz - bf2f(ho.z));
        ho.w = f2bf(vw); lo.w = f2bf(vw - bf2f(ho.w));
        const size_t ob = (size_t)node * 512 + slot * 4;
        *(ushort4*)&out_h[ob] = ho;
        *(ushort4*)&out_l[ob] = lo;
    }
}

// ---------------- small GEMM: h3[M,10] = A[M,512] @ Wc, A = hi/lo bf16 planes ----------------

__global__ __launch_bounds__(256) void gemm_small_kernel(
    const unsigned short* __restrict__ Ahp, const unsigned short* __restrict__ Alp,
    const float* __restrict__ W, float* __restrict__ C, int M, int K)
{
    __shared__ float Ws[512 * 10];
    for (int i = threadIdx.x; i < K * 10; i += blockDim.x) Ws[i] = W[i];
    __syncthreads();

    const int wave = threadIdx.x >> 6;
    const int lane = threadIdx.x & 63;
    const int row = blockIdx.x * (blockDim.x >> 6) + wave;
    if (row >= M) return;

    float acc[10];
#pragma unroll
    for (int c = 0; c < 10; c++) acc[c] = 0.f;

    for (int k = lane; k < K; k += 64) {
        float a = bf2f(Ahp[(size_t)row * K + k]) + bf2f(Alp[(size_t)row * K + k]);
#pragma unroll
        for (int c = 0; c < 10; c++) acc[c] += a * Ws[k * 10 + c];
    }
#pragma unroll
    for (int c = 0; c < 10; c++) {
#pragma unroll
        for (int off = 32; off; off >>= 1) acc[c] += __shfl_down(acc[c], off);
    }
    if (lane == 0) {
#pragma unroll
        for (int c = 0; c < 10; c++) C[(size_t)row * 10 + c] = acc[c];
    }
}

// ---------------- fused gather(F=10) + log_softmax ----------------
// 256 threads = 4 waves; each wave handles 6 nodes (lanes 0..59: node=lane/10, class=lane%10).

__global__ __launch_bounds__(256) void gather10_softmax_kernel(
    const float* __restrict__ h3, float* __restrict__ out,
    const int* __restrict__ csr_src, const int* __restrict__ row_start,
    const float* __restrict__ dinv, const float* __restrict__ bc, int n)
{
    const int wv = threadIdx.x >> 6;
    const int lane = threadIdx.x & 63;
    const int g = lane / 10;
    const int c = lane - g * 10;
    const int node = blockIdx.x * 24 + wv * 6 + g;
    const bool active = (lane < 60) && (node < n);

    float acc = 0.f;
    if (active) {
        float di = dinv[node];
        acc = h3[(size_t)node * 10 + c] * di * di + bc[c];
        int beg = row_start[node], end = row_start[node + 1];
        for (int p = beg; p < end; ++p) {
            int s = csr_src[p];
            acc += h3[(size_t)s * 10 + c] * dinv[s] * di;
        }
    }
    const int base = g * 10;
    float vj[10];
#pragma unroll
    for (int j = 0; j < 10; j++) vj[j] = __shfl(acc, base + j);
    if (active) {
        float m = vj[0];
#pragma unroll
        for (int j = 1; j < 10; j++) m = fmaxf(m, vj[j]);
        float ssum = 0.f;
#pragma unroll
        for (int j = 0; j < 10; j++) ssum += __expf(vj[j] - m);
        out[(size_t)node * 10 + c] = acc - (m + __logf(ssum));
    }
}

// ---------------- launch ----------------

extern "C" void kernel_launch(void* const* d_in, const int* in_sizes, int n_in,
                              void* d_out, int out_size, void* d_ws, size_t ws_size,
                              hipStream_t stream)
{
    const float* x   = (const float*)d_in[0];
    const int*   ei  = (const int*)d_in[1];
    const float* W1  = (const float*)d_in[2];
    const float* b1  = (const float*)d_in[3];
    const float* W2  = (const float*)d_in[4];
    const float* b2  = (const float*)d_in[5];
    const float* Wc  = (const float*)d_in[6];
    const float* bc  = (const float*)d_in[7];
    float* out = (float*)d_out;

    const int IN_FEATS = 784;
    const int KP1 = 800;
    const int H = 512;
    const int NC = 10;
    const int n = in_sizes[0] / IN_FEATS;   // 10000
    const int E = in_sizes[1] / 2;          // 160000
    const int* src = ei;
    const int* dst = ei + E;

    // workspace layout (~66 MB)
    char* ws = (char*)d_ws;
    unsigned short* Hb   = (unsigned short*)ws; ws += (size_t)n * H * sizeof(unsigned short);   // 10.24 MB
    unsigned short* Xh   = (unsigned short*)ws; ws += (size_t)n * KP1 * sizeof(unsigned short); // 16 MB
    unsigned short* Xl   = (unsigned short*)ws; ws += (size_t)n * KP1 * sizeof(unsigned short); // 16 MB
    unsigned short* AhB  = (unsigned short*)ws; ws += (size_t)n * H * sizeof(unsigned short);   // 10.24 MB
    unsigned short* AlB  = (unsigned short*)ws; ws += (size_t)n * H * sizeof(unsigned short);   // 10.24 MB
    unsigned short* W1hT = (unsigned short*)ws; ws += (size_t)KP1 * H * sizeof(unsigned short);
    unsigned short* W1lT = (unsigned short*)ws; ws += (size_t)KP1 * H * sizeof(unsigned short);
    unsigned short* W2hT = (unsigned short*)ws; ws += (size_t)H * H * sizeof(unsigned short);
    unsigned short* W2lT = (unsigned short*)ws; ws += (size_t)H * H * sizeof(unsigned short);
    float* dinv      = (float*)ws;             ws += (size_t)n * sizeof(float);
    int*   deg       = (int*)ws;               ws += (size_t)n * sizeof(int);
    int*   cursor    = (int*)ws;               ws += (size_t)n * sizeof(int);
    int*   csr_src   = (int*)ws;               ws += (size_t)E * sizeof(int);
    int*   row_start = (int*)ws;               ws += (size_t)(n + 1) * sizeof(int);
    float* h3        = (float*)ws;             ws += (size_t)n * NC * sizeof(float);

    hipMemsetAsync(deg, 0, (size_t)n * sizeof(int), stream);
    hipMemsetAsync(cursor, 0, (size_t)n * sizeof(int), stream);

    // ---- fused prep: X/W1/W2 splits + degree count ----
    const int bX  = ((size_t)n * KP1 + 255) / 256;   // 31250
    const int bW1 = (H * KP1 + 255) / 256;           // 1600
    const int bW2 = (H * H + 255) / 256;             // 1024
    const int bE  = (E + 255) / 256;                 // 625
    prep_kernel<<<bX + bW1 + bW2 + bE, 256, 0, stream>>>(
        x, Xh, Xl, W1, W1hT, W1lT, W2, W2hT, W2lT, dst, deg,
        n, IN_FEATS, KP1, H, E, bX, bW1, bW2);

    scan_kernel<<<1, 1024, 0, stream>>>(deg, row_start, dinv, n);
    fill_csr_kernel<<<(E + 255) / 256, 256, 0, stream>>>(src, dst, row_start, cursor, csr_src, E);

    const int tiles_m = (n + TBM - 1) / TBM;                 // 79
    const int gemm_grid = ((tiles_m + 7) / 8) * 64;          // 640

    // ---- layer 1 ----
    gemm_mfma_kernel<<<gemm_grid, 256, 0, stream>>>(Xh, Xl, W1hT, W1lT, Hb, n, H, KP1, tiles_m);
    gather512_kernel<<<n, 256, 0, stream>>>(Hb, AhB, AlB, csr_src, row_start, dinv, b1, n);

    // ---- layer 2 ----
    gemm_mfma_kernel<<<gemm_grid, 256, 0, stream>>>(AhB, AlB, W2hT, W2lT, Hb, n, H, H, tiles_m);
    gather512_kernel<<<n, 256, 0, stream>>>(Hb, AhB, AlB, csr_src, row_start, dinv, b2, n);

    // ---- layer 3 + softmax ----
    gemm_small_kernel<<<(n + 3) / 4, 256, 0, stream>>>(AhB, AlB, Wc, h3, n, H);
    gather10_softmax_kernel<<<(n + 23) / 24, 256, 0, stream>>>(h3, out, csr_src, row_start, dinv, bc, n);
}